// Round 1
// baseline (980.596 us; speedup 1.0000x reference)
//
#include <hip/hip_runtime.h>
#include <hip/hip_bf16.h>
#include <math.h>

#define NDIM 256
#define NH 8
#define HDIM 32

// ---------- bf16 helpers (storage as unsigned short) ----------
__device__ inline float bf2f(unsigned short u) {
  union { unsigned int i; float f; } c; c.i = ((unsigned int)u) << 16; return c.f;
}
__device__ inline unsigned short f2bf(float f) {
  union { float f; unsigned int i; } c; c.f = f;
  unsigned int x = c.i;
  unsigned int lsb = (x >> 16) & 1u;
  x += 0x7fffu + lsb;
  return (unsigned short)(x >> 16);
}
__device__ inline float4 ldbf4(const unsigned short* p) {
  unsigned long long raw = *(const unsigned long long*)p;
  float4 f;
  f.x = bf2f((unsigned short)(raw));
  f.y = bf2f((unsigned short)(raw >> 16));
  f.z = bf2f((unsigned short)(raw >> 32));
  f.w = bf2f((unsigned short)(raw >> 48));
  return f;
}
__device__ inline void stbf4(unsigned short* p, float4 v) {
  unsigned long long raw = (unsigned long long)f2bf(v.x)
                         | ((unsigned long long)f2bf(v.y) << 16)
                         | ((unsigned long long)f2bf(v.z) << 32)
                         | ((unsigned long long)f2bf(v.w) << 48);
  *(unsigned long long*)p = raw;
}

template<typename T> __device__ inline float4 lda4(const T* p);
template<> __device__ inline float4 lda4<float>(const float* p) { return *(const float4*)p; }
template<> __device__ inline float4 lda4<unsigned short>(const unsigned short* p) { return ldbf4(p); }

// ---------- CSR build ----------
__global__ void hist_k(const int* __restrict__ dst, int* __restrict__ deg, int E) {
  int e = blockIdx.x * 256 + threadIdx.x;
  if (e < E) atomicAdd(&deg[dst[e]], 1);
}

__global__ __launch_bounds__(1024) void scan_k(const int* __restrict__ deg, int* __restrict__ offs, int n) {
  __shared__ int wsum[16];
  __shared__ int carry_s;
  int tid = threadIdx.x;
  int lane = tid & 63, wid = tid >> 6;
  if (tid == 0) carry_s = 0;
  __syncthreads();
  for (int base = 0; base < n; base += 1024) {
    int i = base + tid;
    int v = (i < n) ? deg[i] : 0;
    int incl = v;
    #pragma unroll
    for (int d = 1; d < 64; d <<= 1) {
      int t = __shfl_up(incl, d);
      if (lane >= d) incl += t;
    }
    if (lane == 63) wsum[wid] = incl;
    __syncthreads();
    if (wid == 0) {
      int s = (lane < 16) ? wsum[lane] : 0;
      #pragma unroll
      for (int d = 1; d < 16; d <<= 1) {
        int t = __shfl_up(s, d);
        if (lane >= d) s += t;
      }
      if (lane < 16) wsum[lane] = s;
    }
    __syncthreads();
    int woff = (wid > 0) ? wsum[wid - 1] : 0;
    int c = carry_s;
    if (i < n) offs[i] = c + woff + incl - v;
    int tot = wsum[15];
    __syncthreads();
    if (tid == 0) carry_s = c + tot;
    __syncthreads();
  }
  if (tid == 0) offs[n] = carry_s;
}

__global__ void scatter_k(const int* __restrict__ src, const int* __restrict__ dst,
                          int* __restrict__ cursor, int* __restrict__ ssrc, int E) {
  int e = blockIdx.x * 256 + threadIdx.x;
  if (e < E) {
    int p = atomicAdd(&cursor[dst[e]], 1);
    ssrc[p] = src[e];
  }
}

// ---------- per-node online-softmax attention (1 wave per node) ----------
__global__ __launch_bounds__(256) void attn_k(
    const unsigned short* __restrict__ Q,
    const unsigned short* __restrict__ Km,
    const unsigned short* __restrict__ Vm,
    const int* __restrict__ offs,
    const int* __restrict__ ssrc,
    unsigned short* __restrict__ agg, int N)
{
  int n = blockIdx.x * 4 + (threadIdx.x >> 6);
  if (n >= N) return;
  int lane = threadIdx.x & 63;
  int col = lane << 2;  // lane covers head (lane>>3), dims (lane&7)*4.. within head
  const float scale = 0.17677669529663689f;
  float4 q4 = ldbf4(Q + (size_t)n * NDIM + col);
  q4.x *= scale; q4.y *= scale; q4.z *= scale; q4.w *= scale;
  int e0 = offs[n], e1 = offs[n + 1];
  float m = -INFINITY, den = 0.f;
  float4 acc = make_float4(0.f, 0.f, 0.f, 0.f);
  for (int e = e0; e < e1; ++e) {
    int s = ssrc[e];
    float4 k4 = ldbf4(Km + (size_t)s * NDIM + col);
    float4 v4 = ldbf4(Vm + (size_t)s * NDIM + col);
    float d = q4.x * k4.x + q4.y * k4.y + q4.z * k4.z + q4.w * k4.w;
    d += __shfl_xor(d, 1);
    d += __shfl_xor(d, 2);
    d += __shfl_xor(d, 4);   // per-head score replicated across the head's 8 lanes
    float nm = fmaxf(m, d);
    float f = __expf(m - nm);   // m=-inf first iter -> 0
    float p = __expf(d - nm);
    den = den * f + p;
    acc.x = acc.x * f + p * v4.x;
    acc.y = acc.y * f + p * v4.y;
    acc.z = acc.z * f + p * v4.z;
    acc.w = acc.w * f + p * v4.w;
    m = nm;
  }
  float inv = (den > 0.f) ? 1.f / den : 0.f;
  acc.x *= inv; acc.y *= inv; acc.z *= inv; acc.w *= inv;
  stbf4(agg + (size_t)n * NDIM + col, acc);
}

// ---------- generic fp32 tiled GEMM: C = [A1|A2] @ W + bias, epilogues ----------
// EPI: 0 = fp32 store, 1 = bf16 store, 2 = gelu + bf16 store, 3 = qkv-split bf16 store
template<int EPI, typename TA1, typename TA2>
__global__ __launch_bounds__(256) void gemm_k(
    const TA1* __restrict__ A1, const TA2* __restrict__ A2,
    const float* __restrict__ W, const float* __restrict__ bias,
    float* __restrict__ Cf, unsigned short* __restrict__ Cb,
    unsigned short* __restrict__ Oq, unsigned short* __restrict__ Ok, unsigned short* __restrict__ Ov,
    int M, int K1, int K, int Ncol)
{
  __shared__ float As[16][128];  // transposed: As[k][m]
  __shared__ float Ws[16][128];
  const int tid = threadIdx.x;
  const int bm = blockIdx.x * 128;
  const int bn = blockIdx.y * 128;
  const int tr = (tid >> 4) << 3;   // 0..120
  const int tc = (tid & 15) << 3;   // 0..120
  float acc[8][8];
  #pragma unroll
  for (int i = 0; i < 8; ++i)
    #pragma unroll
    for (int j = 0; j < 8; ++j) acc[i][j] = 0.f;

  for (int k0 = 0; k0 < K; k0 += 16) {
    // stage A tile (128 x 16), transposed into As
    #pragma unroll
    for (int t = 0; t < 2; ++t) {
      int idx = tid + t * 256;        // 0..511
      int r = idx >> 2;               // 0..127
      int c = (idx & 3) << 2;         // 0,4,8,12
      int gr = bm + r;
      int gk = k0 + c;
      float4 av = make_float4(0.f, 0.f, 0.f, 0.f);
      if (gr < M) {
        if (gk < K1) av = lda4(A1 + (size_t)gr * K1 + gk);
        else         av = lda4(A2 + (size_t)gr * (K - K1) + (gk - K1));
      }
      As[c + 0][r] = av.x; As[c + 1][r] = av.y; As[c + 2][r] = av.z; As[c + 3][r] = av.w;
    }
    // stage W tile (16 x 128)
    #pragma unroll
    for (int t = 0; t < 2; ++t) {
      int idx = tid + t * 256;
      int r = idx >> 5;               // 0..15
      int c = (idx & 31) << 2;        // 0..124
      *(float4*)&Ws[r][c] = *(const float4*)(W + (size_t)(k0 + r) * Ncol + bn + c);
    }
    __syncthreads();
    #pragma unroll
    for (int kk = 0; kk < 16; ++kk) {
      float4 a0 = *(const float4*)&As[kk][tr];
      float4 a1 = *(const float4*)&As[kk][tr + 4];
      float4 b0 = *(const float4*)&Ws[kk][tc];
      float4 b1 = *(const float4*)&Ws[kk][tc + 4];
      float av[8] = {a0.x, a0.y, a0.z, a0.w, a1.x, a1.y, a1.z, a1.w};
      float bv[8] = {b0.x, b0.y, b0.z, b0.w, b1.x, b1.y, b1.z, b1.w};
      #pragma unroll
      for (int i = 0; i < 8; ++i)
        #pragma unroll
        for (int j = 0; j < 8; ++j)
          acc[i][j] += av[i] * bv[j];
    }
    __syncthreads();
  }

  float bb[8];
  #pragma unroll
  for (int j = 0; j < 8; ++j) bb[j] = bias[bn + tc + j];

  #pragma unroll
  for (int i = 0; i < 8; ++i) {
    int gr = bm + tr + i;
    if (gr >= M) continue;
    #pragma unroll
    for (int j = 0; j < 8; ++j) {
      float val = acc[i][j] + bb[j];
      int gc = bn + tc + j;
      if (EPI == 0) {
        Cf[(size_t)gr * Ncol + gc] = val;
      } else if (EPI == 1) {
        Cb[(size_t)gr * Ncol + gc] = f2bf(val);
      } else if (EPI == 2) {
        val = 0.5f * val * (1.0f + erff(val * 0.70710678118654752f));
        Cb[(size_t)gr * Ncol + gc] = f2bf(val);
      } else {
        int h = gc / 96;
        int t = gc - h * 96;
        unsigned short b16 = f2bf(val);
        if (t < HDIM)          Oq[(size_t)gr * NDIM + h * HDIM + t] = b16;
        else if (t < 2 * HDIM) Ok[(size_t)gr * NDIM + h * HDIM + (t - HDIM)] = b16;
        else                   Ov[(size_t)gr * NDIM + h * HDIM + (t - 2 * HDIM)] = b16;
      }
    }
  }
}

extern "C" void kernel_launch(void* const* d_in, const int* in_sizes, int n_in,
                              void* d_out, int out_size, void* d_ws, size_t ws_size,
                              hipStream_t stream) {
  (void)n_in; (void)out_size; (void)ws_size;
  const float* x    = (const float*)d_in[0];
  const int*   src  = (const int*)d_in[1];
  const int*   dst  = (const int*)d_in[2];
  const float* Wqkv = (const float*)d_in[3];
  const float* bqkv = (const float*)d_in[4];
  const float* Wout = (const float*)d_in[5];
  const float* bout = (const float*)d_in[6];
  const float* W1   = (const float*)d_in[7];
  const float* b1   = (const float*)d_in[8];
  const float* W2   = (const float*)d_in[9];
  const float* b2   = (const float*)d_in[10];
  float* out = (float*)d_out;

  const int N = in_sizes[0] / NDIM;   // 50000
  const int E = in_sizes[1];          // 800000

  char* ws = (char*)d_ws;
  size_t off = 0;
  auto alloc = [&](size_t bytes) -> char* {
    char* p = ws + off;
    off += (bytes + 255) & ~(size_t)255;
    return p;
  };
  unsigned short* Q    = (unsigned short*)alloc((size_t)N * NDIM * 2);
  unsigned short* Km   = (unsigned short*)alloc((size_t)N * NDIM * 2);
  unsigned short* Vm   = (unsigned short*)alloc((size_t)N * NDIM * 2);
  unsigned short* agg  = (unsigned short*)alloc((size_t)N * NDIM * 2);
  int* deg    = (int*)alloc((size_t)N * 4);
  int* offs   = (int*)alloc((size_t)(N + 1) * 4);
  int* cursor = (int*)alloc((size_t)N * 4);
  int* ssrc   = (int*)alloc((size_t)E * 4);
  unsigned short* aggout = Q;   // reuse after attention
  unsigned short* h1     = Km;  // reuse after attention

  // CSR build
  hipMemsetAsync(deg, 0, (size_t)N * 4, stream);
  hist_k<<<(E + 255) / 256, 256, 0, stream>>>(dst, deg, E);
  scan_k<<<1, 1024, 0, stream>>>(deg, offs, N);
  hipMemcpyAsync(cursor, offs, (size_t)N * 4, hipMemcpyDeviceToDevice, stream);
  scatter_k<<<(E + 255) / 256, 256, 0, stream>>>(src, dst, cursor, ssrc, E);

  const int mt = (N + 127) / 128;

  // QKV projection -> q,k,v (bf16, head-contiguous layout)
  gemm_k<3, float, float><<<dim3(mt, 6), 256, 0, stream>>>(
      x, (const float*)nullptr, Wqkv, bqkv, nullptr, nullptr, Q, Km, Vm, N, 256, 256, 768);

  // edge-softmax aggregation
  attn_k<<<(N + 3) / 4, 256, 0, stream>>>(Q, Km, Vm, offs, ssrc, agg, N);

  // agg @ Wout + bout -> aggout (bf16)
  gemm_k<1, unsigned short, float><<<dim3(mt, 2), 256, 0, stream>>>(
      agg, (const float*)nullptr, Wout, bout, nullptr, aggout, nullptr, nullptr, nullptr, N, 256, 256, 256);

  // gelu([x | aggout] @ W1 + b1) -> h1 (bf16)
  gemm_k<2, float, unsigned short><<<dim3(mt, 2), 256, 0, stream>>>(
      x, aggout, W1, b1, nullptr, h1, nullptr, nullptr, nullptr, N, 256, 512, 256);

  // h1 @ W2 + b2 -> out (fp32)
  gemm_k<0, unsigned short, float><<<dim3(mt, 2), 256, 0, stream>>>(
      h1, (const float*)nullptr, W2, b2, out, nullptr, nullptr, nullptr, nullptr, N, 256, 256, 256);
}

// Round 2
// 516.543 us; speedup vs baseline: 1.8984x; 1.8984x over previous
//
#include <hip/hip_runtime.h>
#include <hip/hip_bf16.h>
#include <math.h>

#define NDIM 256
#define NH 8
#define HDIM 32

typedef __attribute__((ext_vector_type(8))) short bf16x8;
typedef __attribute__((ext_vector_type(4))) float f32x4;

// ---------- bf16 helpers ----------
__device__ inline float bf2f(unsigned short u) {
  union { unsigned int i; float f; } c; c.i = ((unsigned int)u) << 16; return c.f;
}
__device__ inline unsigned short f2bf(float f) {
  union { float f; unsigned int i; } c; c.f = f;
  unsigned int x = c.i;
  unsigned int lsb = (x >> 16) & 1u;
  x += 0x7fffu + lsb;
  return (unsigned short)(x >> 16);
}
__device__ inline float4 ldbf4(const unsigned short* p) {
  unsigned long long raw = *(const unsigned long long*)p;
  float4 f;
  f.x = bf2f((unsigned short)(raw));
  f.y = bf2f((unsigned short)(raw >> 16));
  f.z = bf2f((unsigned short)(raw >> 32));
  f.w = bf2f((unsigned short)(raw >> 48));
  return f;
}
__device__ inline void stbf4(unsigned short* p, float4 v) {
  unsigned long long raw = (unsigned long long)f2bf(v.x)
                         | ((unsigned long long)f2bf(v.y) << 16)
                         | ((unsigned long long)f2bf(v.z) << 32)
                         | ((unsigned long long)f2bf(v.w) << 48);
  *(unsigned long long*)p = raw;
}

// ---------- CSR build ----------
__global__ void hist_k(const int* __restrict__ dst, int* __restrict__ deg, int E) {
  int e = blockIdx.x * 256 + threadIdx.x;
  if (e < E) atomicAdd(&deg[dst[e]], 1);
}

__global__ __launch_bounds__(1024) void scan_k(const int* __restrict__ deg, int* __restrict__ offs, int n) {
  __shared__ int wsum[16];
  __shared__ int carry_s;
  int tid = threadIdx.x;
  int lane = tid & 63, wid = tid >> 6;
  if (tid == 0) carry_s = 0;
  __syncthreads();
  for (int base = 0; base < n; base += 1024) {
    int i = base + tid;
    int v = (i < n) ? deg[i] : 0;
    int incl = v;
    #pragma unroll
    for (int d = 1; d < 64; d <<= 1) {
      int t = __shfl_up(incl, d);
      if (lane >= d) incl += t;
    }
    if (lane == 63) wsum[wid] = incl;
    __syncthreads();
    if (wid == 0) {
      int s = (lane < 16) ? wsum[lane] : 0;
      #pragma unroll
      for (int d = 1; d < 16; d <<= 1) {
        int t = __shfl_up(s, d);
        if (lane >= d) s += t;
      }
      if (lane < 16) wsum[lane] = s;
    }
    __syncthreads();
    int woff = (wid > 0) ? wsum[wid - 1] : 0;
    int c = carry_s;
    if (i < n) offs[i] = c + woff + incl - v;
    int tot = wsum[15];
    __syncthreads();
    if (tid == 0) carry_s = c + tot;
    __syncthreads();
  }
  if (tid == 0) offs[n] = carry_s;
}

__global__ void scatter_k(const int* __restrict__ src, const int* __restrict__ dst,
                          int* __restrict__ cursor, int* __restrict__ ssrc, int E) {
  int e = blockIdx.x * 256 + threadIdx.x;
  if (e < E) {
    int p = atomicAdd(&cursor[dst[e]], 1);
    ssrc[p] = src[e];
  }
}

// ---------- per-node online-softmax attention (1 wave per node) ----------
__global__ __launch_bounds__(256) void attn_k(
    const unsigned short* __restrict__ Q,
    const unsigned short* __restrict__ Km,
    const unsigned short* __restrict__ Vm,
    const int* __restrict__ offs,
    const int* __restrict__ ssrc,
    unsigned short* __restrict__ agg, int N)
{
  int n = blockIdx.x * 4 + (threadIdx.x >> 6);
  if (n >= N) return;
  int lane = threadIdx.x & 63;
  int col = lane << 2;
  const float scale = 0.17677669529663689f;
  float4 q4 = ldbf4(Q + (size_t)n * NDIM + col);
  q4.x *= scale; q4.y *= scale; q4.z *= scale; q4.w *= scale;
  int e0 = offs[n], e1 = offs[n + 1];
  float m = -INFINITY, den = 0.f;
  float4 acc = make_float4(0.f, 0.f, 0.f, 0.f);
  for (int e = e0; e < e1; ++e) {
    int s = ssrc[e];
    float4 k4 = ldbf4(Km + (size_t)s * NDIM + col);
    float4 v4 = ldbf4(Vm + (size_t)s * NDIM + col);
    float d = q4.x * k4.x + q4.y * k4.y + q4.z * k4.z + q4.w * k4.w;
    d += __shfl_xor(d, 1);
    d += __shfl_xor(d, 2);
    d += __shfl_xor(d, 4);
    float nm = fmaxf(m, d);
    float f = __expf(m - nm);
    float p = __expf(d - nm);
    den = den * f + p;
    acc.x = acc.x * f + p * v4.x;
    acc.y = acc.y * f + p * v4.y;
    acc.z = acc.z * f + p * v4.z;
    acc.w = acc.w * f + p * v4.w;
    m = nm;
  }
  float inv = (den > 0.f) ? 1.f / den : 0.f;
  acc.x *= inv; acc.y *= inv; acc.z *= inv; acc.w *= inv;
  stbf4(agg + (size_t)n * NDIM + col, acc);
}

// ---------- weight transpose + bf16 convert: Wt[n][k] = bf16(W[k][n]) ----------
__global__ void wconv_k(const float* __restrict__ W, unsigned short* __restrict__ Wt,
                        int K, int Ncol) {
  int idx = blockIdx.x * 256 + threadIdx.x;
  if (idx < K * Ncol) {
    int n = idx / K;
    int k = idx - n * K;
    Wt[idx] = f2bf(W[(size_t)k * Ncol + n]);
  }
}

// ---------- load 8 elements -> bf16x8 ----------
template<bool F32>
__device__ inline bf16x8 ld8(const void* p, size_t off) {
  bf16x8 r;
  if constexpr (F32) {
    const float* f = (const float*)p + off;
    float4 a = *(const float4*)f;
    float4 b = *(const float4*)(f + 4);
    r[0] = (short)f2bf(a.x); r[1] = (short)f2bf(a.y);
    r[2] = (short)f2bf(a.z); r[3] = (short)f2bf(a.w);
    r[4] = (short)f2bf(b.x); r[5] = (short)f2bf(b.y);
    r[6] = (short)f2bf(b.z); r[7] = (short)f2bf(b.w);
  } else {
    r = *(const bf16x8*)((const unsigned short*)p + off);
  }
  return r;
}

// ---------- MFMA GEMM: C[M x Ncol] = [A1|A2][M x K] @ Wt[Ncol x K]^T + bias ----------
// EPI: 0 = fp32 store, 1 = bf16 store, 2 = gelu + bf16 store, 3 = qkv-split bf16 store
template<int EPI, bool A1F, bool A2F>
__global__ __launch_bounds__(256) void mgemm_k(
    const void* __restrict__ A1, const void* __restrict__ A2,
    const unsigned short* __restrict__ Wt, const float* __restrict__ bias,
    float* __restrict__ Cf, unsigned short* __restrict__ Cb,
    unsigned short* __restrict__ Oq, unsigned short* __restrict__ Ok, unsigned short* __restrict__ Ov,
    int M, int K1, int K, int Ncol)
{
  constexpr int LDT = 72;           // 144B row stride: rows advance 4 banks -> 2-way max
  __shared__ unsigned short As[128 * LDT];
  __shared__ unsigned short Bs[128 * LDT];
  const int tid = threadIdx.x;
  const int lane = tid & 63;
  const int wid = tid >> 6;
  const int wr = (wid >> 1) << 6;   // 0 / 64
  const int wc = (wid & 1) << 6;    // 0 / 64
  const int bm = blockIdx.x * 128;
  const int bn = blockIdx.y * 128;
  const int l15 = lane & 15, lhi = lane >> 4;

  f32x4 acc[4][4];
  #pragma unroll
  for (int i = 0; i < 4; ++i)
    #pragma unroll
    for (int j = 0; j < 4; ++j) acc[i][j] = (f32x4){0.f, 0.f, 0.f, 0.f};

  const int lda1 = K1, lda2 = K - K1;

  for (int k0 = 0; k0 < K; k0 += 64) {
    // stage A tile (128 rows x 64 k), bf16
    #pragma unroll
    for (int t = 0; t < 4; ++t) {
      int idx = tid + t * 256;
      int r = idx >> 3;
      int kc = (idx & 7) << 3;
      int gr = bm + r, gk = k0 + kc;
      bf16x8 v = (bf16x8){0,0,0,0,0,0,0,0};
      if (gr < M) {
        if (gk < K1) v = ld8<A1F>(A1, (size_t)gr * lda1 + gk);
        else         v = ld8<A2F>(A2, (size_t)gr * lda2 + (gk - K1));
      }
      *(bf16x8*)&As[r * LDT + kc] = v;
    }
    // stage B tile (128 n-rows x 64 k) from Wt[Ncol][K]
    #pragma unroll
    for (int t = 0; t < 4; ++t) {
      int idx = tid + t * 256;
      int r = idx >> 3;
      int kc = (idx & 7) << 3;
      bf16x8 v = *(const bf16x8*)&Wt[(size_t)(bn + r) * K + k0 + kc];
      *(bf16x8*)&Bs[r * LDT + kc] = v;
    }
    __syncthreads();
    #pragma unroll
    for (int kk = 0; kk < 64; kk += 32) {
      bf16x8 af[4], bf[4];
      #pragma unroll
      for (int mi = 0; mi < 4; ++mi)
        af[mi] = *(const bf16x8*)&As[(wr + mi * 16 + l15) * LDT + kk + lhi * 8];
      #pragma unroll
      for (int ni = 0; ni < 4; ++ni)
        bf[ni] = *(const bf16x8*)&Bs[(wc + ni * 16 + l15) * LDT + kk + lhi * 8];
      #pragma unroll
      for (int mi = 0; mi < 4; ++mi)
        #pragma unroll
        for (int ni = 0; ni < 4; ++ni)
          acc[mi][ni] = __builtin_amdgcn_mfma_f32_16x16x32_bf16(af[mi], bf[ni], acc[mi][ni], 0, 0, 0);
    }
    __syncthreads();
  }

  // epilogue: lane holds C[bm+wr+mi*16+lhi*4+i][bn+wc+ni*16+l15]
  #pragma unroll
  for (int ni = 0; ni < 4; ++ni) {
    int gc = bn + wc + ni * 16 + l15;
    float bb = bias[gc];
    int h, tq;
    if (EPI == 3) { h = gc / 96; tq = gc - h * 96; }
    #pragma unroll
    for (int mi = 0; mi < 4; ++mi) {
      #pragma unroll
      for (int i = 0; i < 4; ++i) {
        int gr = bm + wr + mi * 16 + (lhi << 2) + i;
        if (gr >= M) continue;
        float val = acc[mi][ni][i] + bb;
        if (EPI == 0) {
          Cf[(size_t)gr * Ncol + gc] = val;
        } else if (EPI == 1) {
          Cb[(size_t)gr * Ncol + gc] = f2bf(val);
        } else if (EPI == 2) {
          val = 0.5f * val * (1.0f + erff(val * 0.70710678118654752f));
          Cb[(size_t)gr * Ncol + gc] = f2bf(val);
        } else {
          unsigned short b16 = f2bf(val);
          if (tq < HDIM)          Oq[(size_t)gr * NDIM + h * HDIM + tq] = b16;
          else if (tq < 2 * HDIM) Ok[(size_t)gr * NDIM + h * HDIM + (tq - HDIM)] = b16;
          else                    Ov[(size_t)gr * NDIM + h * HDIM + (tq - 2 * HDIM)] = b16;
        }
      }
    }
  }
}

extern "C" void kernel_launch(void* const* d_in, const int* in_sizes, int n_in,
                              void* d_out, int out_size, void* d_ws, size_t ws_size,
                              hipStream_t stream) {
  (void)n_in; (void)out_size; (void)ws_size;
  const float* x    = (const float*)d_in[0];
  const int*   src  = (const int*)d_in[1];
  const int*   dst  = (const int*)d_in[2];
  const float* Wqkv = (const float*)d_in[3];
  const float* bqkv = (const float*)d_in[4];
  const float* Wout = (const float*)d_in[5];
  const float* bout = (const float*)d_in[6];
  const float* W1   = (const float*)d_in[7];
  const float* b1   = (const float*)d_in[8];
  const float* W2   = (const float*)d_in[9];
  const float* b2   = (const float*)d_in[10];
  float* out = (float*)d_out;

  const int N = in_sizes[0] / NDIM;   // 50000
  const int E = in_sizes[1];          // 800000

  char* ws = (char*)d_ws;
  size_t off = 0;
  auto alloc = [&](size_t bytes) -> char* {
    char* p = ws + off;
    off += (bytes + 255) & ~(size_t)255;
    return p;
  };
  unsigned short* Q    = (unsigned short*)alloc((size_t)N * NDIM * 2);
  unsigned short* Kb   = (unsigned short*)alloc((size_t)N * NDIM * 2);
  unsigned short* Vb   = (unsigned short*)alloc((size_t)N * NDIM * 2);
  unsigned short* agg  = (unsigned short*)alloc((size_t)N * NDIM * 2);
  unsigned short* wqkvt = (unsigned short*)alloc((size_t)768 * 256 * 2);
  unsigned short* woutt = (unsigned short*)alloc((size_t)256 * 256 * 2);
  unsigned short* w1t   = (unsigned short*)alloc((size_t)256 * 512 * 2);
  unsigned short* w2t   = (unsigned short*)alloc((size_t)256 * 256 * 2);
  int* deg    = (int*)alloc((size_t)N * 4);
  int* offs   = (int*)alloc((size_t)(N + 1) * 4);
  int* cursor = (int*)alloc((size_t)N * 4);
  int* ssrc   = (int*)alloc((size_t)E * 4);
  unsigned short* aggout = Kb;   // reuse after attention
  unsigned short* h1     = Vb;   // reuse after attention

  // weight prep
  wconv_k<<<(256 * 768 + 255) / 256, 256, 0, stream>>>(Wqkv, wqkvt, 256, 768);
  wconv_k<<<(256 * 256 + 255) / 256, 256, 0, stream>>>(Wout, woutt, 256, 256);
  wconv_k<<<(512 * 256 + 255) / 256, 256, 0, stream>>>(W1, w1t, 512, 256);
  wconv_k<<<(256 * 256 + 255) / 256, 256, 0, stream>>>(W2, w2t, 256, 256);

  // CSR build
  hipMemsetAsync(deg, 0, (size_t)N * 4, stream);
  hist_k<<<(E + 255) / 256, 256, 0, stream>>>(dst, deg, E);
  scan_k<<<1, 1024, 0, stream>>>(deg, offs, N);
  hipMemcpyAsync(cursor, offs, (size_t)N * 4, hipMemcpyDeviceToDevice, stream);
  scatter_k<<<(E + 255) / 256, 256, 0, stream>>>(src, dst, cursor, ssrc, E);

  const int mt = (N + 127) / 128;

  // QKV projection -> q,k,v (bf16, head-contiguous)
  mgemm_k<3, true, true><<<dim3(mt, 6), 256, 0, stream>>>(
      x, nullptr, wqkvt, bqkv, nullptr, nullptr, Q, Kb, Vb, N, 256, 256, 768);

  // edge-softmax aggregation
  attn_k<<<(N + 3) / 4, 256, 0, stream>>>(Q, Kb, Vb, offs, ssrc, agg, N);

  // agg @ Wout + bout -> aggout (bf16)
  mgemm_k<1, false, false><<<dim3(mt, 2), 256, 0, stream>>>(
      agg, nullptr, woutt, bout, nullptr, aggout, nullptr, nullptr, nullptr, N, 256, 256, 256);

  // gelu([x | aggout] @ W1 + b1) -> h1 (bf16)
  mgemm_k<2, true, false><<<dim3(mt, 2), 256, 0, stream>>>(
      x, aggout, w1t, b1, nullptr, h1, nullptr, nullptr, nullptr, N, 256, 512, 256);

  // h1 @ W2 + b2 -> out (fp32)
  mgemm_k<0, false, false><<<dim3(mt, 2), 256, 0, stream>>>(
      h1, nullptr, w2t, b2, out, nullptr, nullptr, nullptr, nullptr, N, 256, 256, 256);
}

// Round 3
// 465.585 us; speedup vs baseline: 2.1062x; 1.1094x over previous
//
#include <hip/hip_runtime.h>
#include <hip/hip_bf16.h>
#include <math.h>

#define NDIM 256
#define HDIM 32

typedef __attribute__((ext_vector_type(8))) short bf16x8;
typedef __attribute__((ext_vector_type(4))) float f32x4;

// ---------- bf16 helpers ----------
__device__ inline float bf2f(unsigned short u) {
  union { unsigned int i; float f; } c; c.i = ((unsigned int)u) << 16; return c.f;
}
__device__ inline unsigned short f2bf(float f) {
  union { float f; unsigned int i; } c; c.f = f;
  unsigned int x = c.i;
  unsigned int lsb = (x >> 16) & 1u;
  x += 0x7fffu + lsb;
  return (unsigned short)(x >> 16);
}
__device__ inline float4 ldbf4(const unsigned short* p) {
  unsigned long long raw = *(const unsigned long long*)p;
  float4 f;
  f.x = bf2f((unsigned short)(raw));
  f.y = bf2f((unsigned short)(raw >> 16));
  f.z = bf2f((unsigned short)(raw >> 32));
  f.w = bf2f((unsigned short)(raw >> 48));
  return f;
}
__device__ inline void stbf4(unsigned short* p, float4 v) {
  unsigned long long raw = (unsigned long long)f2bf(v.x)
                         | ((unsigned long long)f2bf(v.y) << 16)
                         | ((unsigned long long)f2bf(v.z) << 32)
                         | ((unsigned long long)f2bf(v.w) << 48);
  *(unsigned long long*)p = raw;
}

// ---------- fp32 -> bf16 bulk convert (8 per thread) ----------
__global__ void xconv_k(const float* __restrict__ x, unsigned short* __restrict__ xb, int n8) {
  int i = blockIdx.x * 256 + threadIdx.x;
  if (i >= n8) return;
  const float* p = x + (size_t)i * 8;
  float4 a = *(const float4*)p;
  float4 b = *(const float4*)(p + 4);
  unsigned long long lo = (unsigned long long)f2bf(a.x) | ((unsigned long long)f2bf(a.y) << 16)
                        | ((unsigned long long)f2bf(a.z) << 32) | ((unsigned long long)f2bf(a.w) << 48);
  unsigned long long hi = (unsigned long long)f2bf(b.x) | ((unsigned long long)f2bf(b.y) << 16)
                        | ((unsigned long long)f2bf(b.z) << 32) | ((unsigned long long)f2bf(b.w) << 48);
  unsigned long long* d = (unsigned long long*)(xb + (size_t)i * 8);
  d[0] = lo; d[1] = hi;
}

// ---------- weight transpose + bf16 convert: Wt[n][k] = bf16(W[k][n]) ----------
__global__ void wconv_k(const float* __restrict__ W, unsigned short* __restrict__ Wt,
                        int K, int Ncol) {
  int idx = blockIdx.x * 256 + threadIdx.x;
  if (idx < K * Ncol) {
    int n = idx / K;
    int k = idx - n * K;
    Wt[idx] = f2bf(W[(size_t)k * Ncol + n]);
  }
}

// ---------- CSR build ----------
__global__ void hist_k(const int* __restrict__ dst, int* __restrict__ deg, int E) {
  int e = blockIdx.x * 256 + threadIdx.x;
  if (e < E) atomicAdd(&deg[dst[e]], 1);
}

__global__ __launch_bounds__(1024) void scan_k(const int* __restrict__ deg, int* __restrict__ offs, int n) {
  __shared__ int wsum[16];
  __shared__ int carry_s;
  int tid = threadIdx.x;
  int lane = tid & 63, wid = tid >> 6;
  if (tid == 0) carry_s = 0;
  __syncthreads();
  for (int base = 0; base < n; base += 1024) {
    int i = base + tid;
    int v = (i < n) ? deg[i] : 0;
    int incl = v;
    #pragma unroll
    for (int d = 1; d < 64; d <<= 1) {
      int t = __shfl_up(incl, d);
      if (lane >= d) incl += t;
    }
    if (lane == 63) wsum[wid] = incl;
    __syncthreads();
    if (wid == 0) {
      int s = (lane < 16) ? wsum[lane] : 0;
      #pragma unroll
      for (int d = 1; d < 16; d <<= 1) {
        int t = __shfl_up(s, d);
        if (lane >= d) s += t;
      }
      if (lane < 16) wsum[lane] = s;
    }
    __syncthreads();
    int woff = (wid > 0) ? wsum[wid - 1] : 0;
    int c = carry_s;
    if (i < n) offs[i] = c + woff + incl - v;
    int tot = wsum[15];
    __syncthreads();
    if (tid == 0) carry_s = c + tot;
    __syncthreads();
  }
  if (tid == 0) offs[n] = carry_s;
}

__global__ void scatter_k(const int* __restrict__ src, const int* __restrict__ dst,
                          int* __restrict__ cursor, int* __restrict__ ssrc, int E) {
  int e = blockIdx.x * 256 + threadIdx.x;
  if (e < E) {
    int p = atomicAdd(&cursor[dst[e]], 1);
    ssrc[p] = src[e];
  }
}

// ---------- per-node online-softmax attention, 4x unrolled edge loop ----------
// NOTE: agg may alias Q (Q[n] is read only by the wave owning node n, before its write)
__global__ __launch_bounds__(256) void attn_k(
    const unsigned short* Q,
    const unsigned short* __restrict__ Km,
    const unsigned short* __restrict__ Vm,
    const int* __restrict__ offs,
    const int* __restrict__ ssrc,
    unsigned short* agg, int N)
{
  int n = blockIdx.x * 4 + (threadIdx.x >> 6);
  if (n >= N) return;
  int lane = threadIdx.x & 63;
  int col = lane << 2;
  const float scale = 0.17677669529663689f;
  float4 q4 = ldbf4(Q + (size_t)n * NDIM + col);
  q4.x *= scale; q4.y *= scale; q4.z *= scale; q4.w *= scale;
  int e0 = offs[n], e1 = offs[n + 1];
  float m = -INFINITY, den = 0.f;
  float4 acc = make_float4(0.f, 0.f, 0.f, 0.f);
  int e = e0;
  for (; e + 4 <= e1; e += 4) {
    int s0 = ssrc[e], s1 = ssrc[e + 1], s2 = ssrc[e + 2], s3 = ssrc[e + 3];
    float4 ka = ldbf4(Km + (size_t)s0 * NDIM + col);
    float4 kb = ldbf4(Km + (size_t)s1 * NDIM + col);
    float4 kc = ldbf4(Km + (size_t)s2 * NDIM + col);
    float4 kd = ldbf4(Km + (size_t)s3 * NDIM + col);
    float4 va = ldbf4(Vm + (size_t)s0 * NDIM + col);
    float4 vb = ldbf4(Vm + (size_t)s1 * NDIM + col);
    float4 vc = ldbf4(Vm + (size_t)s2 * NDIM + col);
    float4 vd = ldbf4(Vm + (size_t)s3 * NDIM + col);
    float d0 = q4.x * ka.x + q4.y * ka.y + q4.z * ka.z + q4.w * ka.w;
    float d1 = q4.x * kb.x + q4.y * kb.y + q4.z * kb.z + q4.w * kb.w;
    float d2 = q4.x * kc.x + q4.y * kc.y + q4.z * kc.z + q4.w * kc.w;
    float d3 = q4.x * kd.x + q4.y * kd.y + q4.z * kd.z + q4.w * kd.w;
    d0 += __shfl_xor(d0, 1); d1 += __shfl_xor(d1, 1); d2 += __shfl_xor(d2, 1); d3 += __shfl_xor(d3, 1);
    d0 += __shfl_xor(d0, 2); d1 += __shfl_xor(d1, 2); d2 += __shfl_xor(d2, 2); d3 += __shfl_xor(d3, 2);
    d0 += __shfl_xor(d0, 4); d1 += __shfl_xor(d1, 4); d2 += __shfl_xor(d2, 4); d3 += __shfl_xor(d3, 4);
    float mx = fmaxf(fmaxf(d0, d1), fmaxf(d2, d3));
    float nm = fmaxf(m, mx);
    float fr = __expf(m - nm);
    float p0 = __expf(d0 - nm), p1 = __expf(d1 - nm);
    float p2 = __expf(d2 - nm), p3 = __expf(d3 - nm);
    den = den * fr + (p0 + p1) + (p2 + p3);
    acc.x = acc.x * fr + p0 * va.x + p1 * vb.x + p2 * vc.x + p3 * vd.x;
    acc.y = acc.y * fr + p0 * va.y + p1 * vb.y + p2 * vc.y + p3 * vd.y;
    acc.z = acc.z * fr + p0 * va.z + p1 * vb.z + p2 * vc.z + p3 * vd.z;
    acc.w = acc.w * fr + p0 * va.w + p1 * vb.w + p2 * vc.w + p3 * vd.w;
    m = nm;
  }
  for (; e < e1; ++e) {
    int s = ssrc[e];
    float4 k4 = ldbf4(Km + (size_t)s * NDIM + col);
    float4 v4 = ldbf4(Vm + (size_t)s * NDIM + col);
    float d = q4.x * k4.x + q4.y * k4.y + q4.z * k4.z + q4.w * k4.w;
    d += __shfl_xor(d, 1);
    d += __shfl_xor(d, 2);
    d += __shfl_xor(d, 4);
    float nm = fmaxf(m, d);
    float fr = __expf(m - nm);
    float p = __expf(d - nm);
    den = den * fr + p;
    acc.x = acc.x * fr + p * v4.x;
    acc.y = acc.y * fr + p * v4.y;
    acc.z = acc.z * fr + p * v4.z;
    acc.w = acc.w * fr + p * v4.w;
    m = nm;
  }
  float inv = (den > 0.f) ? 1.f / den : 0.f;
  acc.x *= inv; acc.y *= inv; acc.z *= inv; acc.w *= inv;
  stbf4(agg + (size_t)n * NDIM + col, acc);
}

// ---------- MFMA GEMM, m97 structure: global_load_lds width-16, linear LDS [128][64] ----------
// A is bf16 row-major with lda=256 (two concat sources A1|A2, split at K1). B = Wt[Ncol][ldb].
// EPI: 0 = fp32 store, 1 = bf16 store, 2 = gelu + bf16 store, 3 = qkv-split bf16 store
template<int EPI>
__global__ __launch_bounds__(256) void mgemm_k(
    const unsigned short* __restrict__ A1, const unsigned short* __restrict__ A2,
    const unsigned short* __restrict__ Wt, const float* __restrict__ bias,
    float* __restrict__ Cf, unsigned short* __restrict__ Cb,
    unsigned short* __restrict__ Oq, unsigned short* __restrict__ Ok, unsigned short* __restrict__ Ov,
    int M, int K1, int K, int Ncol, int ldb)
{
  __shared__ unsigned short As[128 * 64];
  __shared__ unsigned short Bs[128 * 64];
  const int tid = threadIdx.x;
  const int lane = tid & 63;
  const int wid = tid >> 6;
  const int bm = blockIdx.x * 128;
  const int bn = blockIdx.y * 128;
  const int wr = (wid >> 1) << 6;
  const int wc = (wid & 1) << 6;
  const int l15 = lane & 15, lhi = lane >> 4;
  const int srow = lane >> 3;          // 0..7
  const int scol = (lane & 7) << 3;    // 0..56 (elements)

  f32x4 acc[4][4];
  #pragma unroll
  for (int i = 0; i < 4; ++i)
    #pragma unroll
    for (int j = 0; j < 4; ++j) acc[i][j] = (f32x4){0.f, 0.f, 0.f, 0.f};

  for (int k0 = 0; k0 < K; k0 += 64) {
    const unsigned short* Ab;
    int ks;
    if (k0 < K1) { Ab = A1; ks = k0; } else { Ab = A2; ks = k0 - K1; }
    // stage A tile (128 x 64) and B tile (128 x 64): 16 KB each, 8 gloads/wave total
    #pragma unroll
    for (int t = 0; t < 4; ++t) {
      int qi = wid * 4 + t;                       // 0..15: rows qi*8 .. qi*8+7
      const unsigned short* ga = Ab + (size_t)(bm + qi * 8 + srow) * 256 + ks + scol;
      __builtin_amdgcn_global_load_lds(
          (const __attribute__((address_space(1))) void*)ga,
          (__attribute__((address_space(3))) void*)&As[qi * 512], 16, 0, 0);
      const unsigned short* gb = Wt + (size_t)(bn + qi * 8 + srow) * ldb + k0 + scol;
      __builtin_amdgcn_global_load_lds(
          (const __attribute__((address_space(1))) void*)gb,
          (__attribute__((address_space(3))) void*)&Bs[qi * 512], 16, 0, 0);
    }
    __syncthreads();
    #pragma unroll
    for (int kk = 0; kk < 64; kk += 32) {
      bf16x8 af[4], bf[4];
      #pragma unroll
      for (int mi = 0; mi < 4; ++mi)
        af[mi] = *(const bf16x8*)&As[(wr + mi * 16 + l15) * 64 + kk + lhi * 8];
      #pragma unroll
      for (int ni = 0; ni < 4; ++ni)
        bf[ni] = *(const bf16x8*)&Bs[(wc + ni * 16 + l15) * 64 + kk + lhi * 8];
      #pragma unroll
      for (int mi = 0; mi < 4; ++mi)
        #pragma unroll
        for (int ni = 0; ni < 4; ++ni)
          acc[mi][ni] = __builtin_amdgcn_mfma_f32_16x16x32_bf16(af[mi], bf[ni], acc[mi][ni], 0, 0, 0);
    }
    __syncthreads();
  }

  // epilogue: lane holds C[bm+wr+mi*16+lhi*4+i][bn+wc+ni*16+l15]
  #pragma unroll
  for (int ni = 0; ni < 4; ++ni) {
    int gc = bn + wc + ni * 16 + l15;
    float bb = bias[gc];
    int h = 0, tq = 0;
    if (EPI == 3) { h = gc / 96; tq = gc - h * 96; }
    #pragma unroll
    for (int mi = 0; mi < 4; ++mi) {
      #pragma unroll
      for (int i = 0; i < 4; ++i) {
        int gr = bm + wr + mi * 16 + (lhi << 2) + i;
        if (gr >= M) continue;
        float val = acc[mi][ni][i] + bb;
        if (EPI == 0) {
          Cf[(size_t)gr * Ncol + gc] = val;
        } else if (EPI == 1) {
          Cb[(size_t)gr * Ncol + gc] = f2bf(val);
        } else if (EPI == 2) {
          val = 0.5f * val * (1.0f + erff(val * 0.70710678118654752f));
          Cb[(size_t)gr * Ncol + gc] = f2bf(val);
        } else {
          unsigned short b16 = f2bf(val);
          if (tq < HDIM)          Oq[(size_t)gr * NDIM + h * HDIM + tq] = b16;
          else if (tq < 2 * HDIM) Ok[(size_t)gr * NDIM + h * HDIM + (tq - HDIM)] = b16;
          else                    Ov[(size_t)gr * NDIM + h * HDIM + (tq - 2 * HDIM)] = b16;
        }
      }
    }
  }
}

extern "C" void kernel_launch(void* const* d_in, const int* in_sizes, int n_in,
                              void* d_out, int out_size, void* d_ws, size_t ws_size,
                              hipStream_t stream) {
  (void)n_in; (void)out_size; (void)ws_size;
  const float* x    = (const float*)d_in[0];
  const int*   src  = (const int*)d_in[1];
  const int*   dst  = (const int*)d_in[2];
  const float* Wqkv = (const float*)d_in[3];
  const float* bqkv = (const float*)d_in[4];
  const float* Wout = (const float*)d_in[5];
  const float* bout = (const float*)d_in[6];
  const float* W1   = (const float*)d_in[7];
  const float* b1   = (const float*)d_in[8];
  const float* W2   = (const float*)d_in[9];
  const float* b2   = (const float*)d_in[10];
  float* out = (float*)d_out;

  const int N = in_sizes[0] / NDIM;   // 50000
  const int E = in_sizes[1];          // 800000
  const int Mp = (N + 127) & ~127;    // 50048 padded rows

  char* ws = (char*)d_ws;
  size_t off = 0;
  auto alloc = [&](size_t bytes) -> char* {
    char* p = ws + off;
    off += (bytes + 255) & ~(size_t)255;
    return p;
  };
  unsigned short* xb   = (unsigned short*)alloc((size_t)Mp * NDIM * 2);
  unsigned short* Q    = (unsigned short*)alloc((size_t)Mp * NDIM * 2);
  unsigned short* Kb   = (unsigned short*)alloc((size_t)Mp * NDIM * 2);
  unsigned short* Vb   = (unsigned short*)alloc((size_t)Mp * NDIM * 2);
  unsigned short* wqkvt = (unsigned short*)alloc((size_t)768 * 256 * 2);
  unsigned short* woutt = (unsigned short*)alloc((size_t)256 * 256 * 2);
  unsigned short* w1t   = (unsigned short*)alloc((size_t)256 * 512 * 2);
  unsigned short* w2t   = (unsigned short*)alloc((size_t)256 * 256 * 2);
  int* deg    = (int*)alloc((size_t)N * 4);
  int* offs   = (int*)alloc((size_t)(N + 1) * 4);
  int* cursor = (int*)alloc((size_t)N * 4);
  int* ssrc   = (int*)alloc((size_t)E * 4);
  unsigned short* agg    = Q;    // in-place: safe, Q[n] read only by node-n's wave first
  unsigned short* aggout = Kb;   // Kb dead after attn
  unsigned short* h1     = Vb;   // Vb dead after attn

  // input/weight prep
  xconv_k<<<(N * NDIM / 8 + 255) / 256, 256, 0, stream>>>(x, xb, N * NDIM / 8);
  wconv_k<<<(256 * 768 + 255) / 256, 256, 0, stream>>>(Wqkv, wqkvt, 256, 768);
  wconv_k<<<(256 * 256 + 255) / 256, 256, 0, stream>>>(Wout, woutt, 256, 256);
  wconv_k<<<(512 * 256 + 255) / 256, 256, 0, stream>>>(W1, w1t, 512, 256);
  wconv_k<<<(256 * 256 + 255) / 256, 256, 0, stream>>>(W2, w2t, 256, 256);

  // CSR build
  hipMemsetAsync(deg, 0, (size_t)N * 4, stream);
  hist_k<<<(E + 255) / 256, 256, 0, stream>>>(dst, deg, E);
  scan_k<<<1, 1024, 0, stream>>>(deg, offs, N);
  hipMemcpyAsync(cursor, offs, (size_t)N * 4, hipMemcpyDeviceToDevice, stream);
  scatter_k<<<(E + 255) / 256, 256, 0, stream>>>(src, dst, cursor, ssrc, E);

  const int mt = Mp / 128;   // 391

  // QKV projection -> q,k,v (bf16, head-contiguous)
  mgemm_k<3><<<dim3(mt, 6), 256, 0, stream>>>(
      xb, nullptr, wqkvt, bqkv, nullptr, nullptr, Q, Kb, Vb, N, 256, 256, 768, 256);

  // edge-softmax aggregation (writes agg == Q in place)
  attn_k<<<(N + 3) / 4, 256, 0, stream>>>(Q, Kb, Vb, offs, ssrc, agg, N);

  // agg @ Wout + bout -> aggout (bf16)
  mgemm_k<1><<<dim3(mt, 2), 256, 0, stream>>>(
      agg, nullptr, woutt, bout, nullptr, aggout, nullptr, nullptr, nullptr, N, 256, 256, 256, 256);

  // gelu([xb | aggout] @ W1 + b1) -> h1 (bf16)
  mgemm_k<2><<<dim3(mt, 2), 256, 0, stream>>>(
      xb, aggout, w1t, b1, nullptr, h1, nullptr, nullptr, nullptr, N, 256, 512, 256, 512);

  // h1 @ W2 + b2 -> out (fp32)
  mgemm_k<0><<<dim3(mt, 2), 256, 0, stream>>>(
      h1, nullptr, w2t, b2, out, nullptr, nullptr, nullptr, nullptr, N, 256, 256, 256, 256);
}

// Round 5
// 374.164 us; speedup vs baseline: 2.6208x; 1.2443x over previous
//
#include <hip/hip_runtime.h>
#include <hip/hip_bf16.h>
#include <math.h>

#define NDIM 256
#define HDIM 32
#define SCB 512

typedef __attribute__((ext_vector_type(8))) short bf16x8;
typedef __attribute__((ext_vector_type(4))) float f32x4;
typedef __attribute__((ext_vector_type(2))) float f32x2;

// ---------- bf16 helpers ----------
__device__ inline float bf2f(unsigned short u) {
  union { unsigned int i; float f; } c; c.i = ((unsigned int)u) << 16; return c.f;
}
__device__ inline unsigned short f2bf(float f) {
  union { float f; unsigned int i; } c; c.f = f;
  unsigned int x = c.i;
  unsigned int lsb = (x >> 16) & 1u;
  x += 0x7fffu + lsb;
  return (unsigned short)(x >> 16);
}
__device__ inline float4 ldbf4(const unsigned short* p) {
  unsigned long long raw = *(const unsigned long long*)p;
  float4 f;
  f.x = bf2f((unsigned short)(raw));
  f.y = bf2f((unsigned short)(raw >> 16));
  f.z = bf2f((unsigned short)(raw >> 32));
  f.w = bf2f((unsigned short)(raw >> 48));
  return f;
}
__device__ inline void stbf4(unsigned short* p, float4 v) {
  unsigned long long raw = (unsigned long long)f2bf(v.x)
                         | ((unsigned long long)f2bf(v.y) << 16)
                         | ((unsigned long long)f2bf(v.z) << 32)
                         | ((unsigned long long)f2bf(v.w) << 48);
  *(unsigned long long*)p = raw;
}

// ---------- fp8 e4m3 helpers (HW cvt with manual fallback) ----------
__device__ inline unsigned char f2e4m3(float v) {
#if __has_builtin(__builtin_amdgcn_cvt_pk_fp8_f32)
  return (unsigned char)(__builtin_amdgcn_cvt_pk_fp8_f32(v, v, 0, false) & 0xff);
#else
  union { float f; unsigned int u; } c; c.f = v;
  unsigned char s = (unsigned char)((c.u >> 24) & 0x80);
  float a = fabsf(v);
  if (!(a < 448.f)) return (unsigned char)(s | 0x7e);
  if (a < 0.0009765625f) return s;                  // < 2^-10 -> 0
  int e = (int)((c.u >> 23) & 0xff) - 127;
  if (e < -6) {                                     // subnormal, step 2^-9
    int q = (int)rintf(ldexpf(a, 9));
    if (q >= 8) return (unsigned char)(s | 0x08);
    return (unsigned char)(s | q);
  }
  int q = (int)rintf(ldexpf(a, 3 - e));             // [8,16]
  if (q == 16) { e++; q = 8; }
  if (e > 8) return (unsigned char)(s | 0x7e);
  return (unsigned char)(s | ((e + 7) << 3) | (q - 8));
#endif
}
template<bool HI>
__device__ inline f32x2 e4m3pk(unsigned int w) {
#if __has_builtin(__builtin_amdgcn_cvt_pk_f32_fp8)
  return __builtin_amdgcn_cvt_pk_f32_fp8((int)w, HI);
#else
  unsigned int h = HI ? (w >> 16) : w;
  f32x2 r;
  #pragma unroll
  for (int j = 0; j < 2; ++j) {
    unsigned char b = (unsigned char)(h >> (8 * j));
    int e = (b >> 3) & 0xf, mm = b & 7;
    float val = e ? ldexpf((float)(8 + mm), e - 10) : ldexpf((float)mm, -9);
    r[j] = (b & 0x80) ? -val : val;
  }
  return r;
#endif
}

// ---------- fp32 -> bf16 bulk convert ----------
__global__ void xconv_k(const float* __restrict__ x, unsigned short* __restrict__ xb, int n8) {
  int i = blockIdx.x * 256 + threadIdx.x;
  if (i >= n8) return;
  const float* p = x + (size_t)i * 8;
  float4 a = *(const float4*)p;
  float4 b = *(const float4*)(p + 4);
  unsigned long long lo = (unsigned long long)f2bf(a.x) | ((unsigned long long)f2bf(a.y) << 16)
                        | ((unsigned long long)f2bf(a.z) << 32) | ((unsigned long long)f2bf(a.w) << 48);
  unsigned long long hi = (unsigned long long)f2bf(b.x) | ((unsigned long long)f2bf(b.y) << 16)
                        | ((unsigned long long)f2bf(b.z) << 32) | ((unsigned long long)f2bf(b.w) << 48);
  unsigned long long* d = (unsigned long long*)(xb + (size_t)i * 8);
  d[0] = lo; d[1] = hi;
}

// ---------- weight transpose + bf16 convert: Wt[n][k] = bf16(W[k][n]) ----------
__global__ void wconv_k(const float* __restrict__ W, unsigned short* __restrict__ Wt,
                        int K, int Ncol) {
  int idx = blockIdx.x * 256 + threadIdx.x;
  if (idx < K * Ncol) {
    int n = idx / K;
    int k = idx - n * K;
    Wt[idx] = f2bf(W[(size_t)k * Ncol + n]);
  }
}

// ---------- CSR build ----------
__global__ void hist_k(const int* __restrict__ dst, int* __restrict__ deg, int E) {
  int e = blockIdx.x * 256 + threadIdx.x;
  if (e < E) atomicAdd(&deg[dst[e]], 1);
}

__global__ __launch_bounds__(SCB) void bsum_k(const int* __restrict__ deg, int* __restrict__ bsum, int n) {
  int tid = threadIdx.x;
  int i = blockIdx.x * SCB + tid;
  int v = (i < n) ? deg[i] : 0;
  #pragma unroll
  for (int d = 1; d < 64; d <<= 1) v += __shfl_xor(v, d);
  __shared__ int wsum[8];
  if ((tid & 63) == 0) wsum[tid >> 6] = v;
  __syncthreads();
  if (tid == 0) {
    int s = 0;
    #pragma unroll
    for (int j = 0; j < 8; ++j) s += wsum[j];
    bsum[blockIdx.x] = s;
  }
}

__global__ __launch_bounds__(128) void bscan_k(int* __restrict__ bsum, int nb) {
  __shared__ int tmp[128];
  int tid = threadIdx.x;
  int v = (tid < nb) ? bsum[tid] : 0;
  tmp[tid] = v;
  __syncthreads();
  for (int d = 1; d < 128; d <<= 1) {
    int t = (tid >= d) ? tmp[tid - d] : 0;
    __syncthreads();
    tmp[tid] += t;
    __syncthreads();
  }
  if (tid < nb) bsum[tid] = tmp[tid];
}

__global__ __launch_bounds__(SCB) void offs_k(const int* __restrict__ deg, const int* __restrict__ bsum,
                                              int* __restrict__ offs, int n) {
  int tid = threadIdx.x, lane = tid & 63, wid = tid >> 6;
  int b = blockIdx.x;
  int i = b * SCB + tid;
  int v = (i < n) ? deg[i] : 0;
  int incl = v;
  #pragma unroll
  for (int d = 1; d < 64; d <<= 1) { int t = __shfl_up(incl, d); if (lane >= d) incl += t; }
  __shared__ int wsum[8];
  if (lane == 63) wsum[wid] = incl;
  __syncthreads();
  if (tid < 8) {
    int s = wsum[tid];
    #pragma unroll
    for (int d = 1; d < 8; d <<= 1) { int t = __shfl_up(s, d); if (tid >= d) s += t; }
    wsum[tid] = s;
  }
  __syncthreads();
  int base = (b > 0 ? bsum[b - 1] : 0) + (wid > 0 ? wsum[wid - 1] : 0);
  if (i < n) offs[i] = base + incl - v;
  if (i == n - 1) offs[n] = base + incl;
}

__global__ void scatter_k(const int* __restrict__ src, const int* __restrict__ dst,
                          int* __restrict__ cursor, int* __restrict__ ssrc, int E) {
  int e = blockIdx.x * 256 + threadIdx.x;
  if (e < E) {
    int p = atomicAdd(&cursor[dst[e]], 1);
    ssrc[p] = src[e];
  }
}

// ---------- per-node online-softmax attention, fp8 K/V, 8x unrolled ----------
// agg aliases Q (node n's Q row read only by node n's wave, before its write)
__global__ __launch_bounds__(256) void attn_k(
    const unsigned short* Q,
    const unsigned char* __restrict__ K8,
    const unsigned char* __restrict__ V8,
    const int* __restrict__ offs,
    const int* __restrict__ ssrc,
    unsigned short* agg, int N)
{
  int n = blockIdx.x * 4 + (threadIdx.x >> 6);
  if (n >= N) return;
  int lane = threadIdx.x & 63;
  int col = lane << 2;
  const float scale = 0.17677669529663689f;
  float4 q4 = ldbf4(Q + (size_t)n * NDIM + col);
  q4.x *= scale; q4.y *= scale; q4.z *= scale; q4.w *= scale;
  int e0 = offs[n], e1 = offs[n + 1];
  float m = -INFINITY, den = 0.f;
  float ax = 0.f, ay = 0.f, az = 0.f, aw = 0.f;
  int e = e0;
  for (; e + 8 <= e1; e += 8) {
    unsigned int kw[8], vw[8];
    #pragma unroll
    for (int j = 0; j < 8; ++j) {
      int s = ssrc[e + j];
      kw[j] = *(const unsigned int*)(K8 + (size_t)s * NDIM + col);
      vw[j] = *(const unsigned int*)(V8 + (size_t)s * NDIM + col);
    }
    float d[8];
    #pragma unroll
    for (int j = 0; j < 8; ++j) {
      f32x2 k01 = e4m3pk<false>(kw[j]);
      f32x2 k23 = e4m3pk<true>(kw[j]);
      d[j] = q4.x * k01[0] + q4.y * k01[1] + q4.z * k23[0] + q4.w * k23[1];
    }
    #pragma unroll
    for (int j = 0; j < 8; ++j) {
      d[j] += __shfl_xor(d[j], 1);
      d[j] += __shfl_xor(d[j], 2);
      d[j] += __shfl_xor(d[j], 4);
    }
    float mx = d[0];
    #pragma unroll
    for (int j = 1; j < 8; ++j) mx = fmaxf(mx, d[j]);
    float nm = fmaxf(m, mx);
    float fr = __expf(m - nm);
    float p[8], ps = 0.f;
    #pragma unroll
    for (int j = 0; j < 8; ++j) { p[j] = __expf(d[j] - nm); ps += p[j]; }
    den = den * fr + ps;
    ax *= fr; ay *= fr; az *= fr; aw *= fr;
    #pragma unroll
    for (int j = 0; j < 8; ++j) {
      f32x2 v01 = e4m3pk<false>(vw[j]);
      f32x2 v23 = e4m3pk<true>(vw[j]);
      ax += p[j] * v01[0]; ay += p[j] * v01[1];
      az += p[j] * v23[0]; aw += p[j] * v23[1];
    }
    m = nm;
  }
  for (; e < e1; ++e) {
    int s = ssrc[e];
    unsigned int kw = *(const unsigned int*)(K8 + (size_t)s * NDIM + col);
    unsigned int vw = *(const unsigned int*)(V8 + (size_t)s * NDIM + col);
    f32x2 k01 = e4m3pk<false>(kw);
    f32x2 k23 = e4m3pk<true>(kw);
    float d = q4.x * k01[0] + q4.y * k01[1] + q4.z * k23[0] + q4.w * k23[1];
    d += __shfl_xor(d, 1);
    d += __shfl_xor(d, 2);
    d += __shfl_xor(d, 4);
    float nm = fmaxf(m, d);
    float fr = __expf(m - nm);
    float p = __expf(d - nm);
    den = den * fr + p;
    f32x2 v01 = e4m3pk<false>(vw);
    f32x2 v23 = e4m3pk<true>(vw);
    ax = ax * fr + p * v01[0]; ay = ay * fr + p * v01[1];
    az = az * fr + p * v23[0]; aw = aw * fr + p * v23[1];
    m = nm;
  }
  float inv = (den > 0.f) ? 1.f / den : 0.f;
  stbf4(agg + (size_t)n * NDIM + col, make_float4(ax * inv, ay * inv, az * inv, aw * inv));
}

// ---------- MFMA GEMM (m97 structure): global_load_lds width-16, linear LDS [128][64] ----------
// EPI: 0 = fp32 store, 1 = bf16 store, 2 = gelu + bf16 store, 3 = qkv split (Q bf16, K/V fp8)
template<int EPI>
__global__ __launch_bounds__(256) void mgemm_k(
    const unsigned short* __restrict__ A1, const unsigned short* __restrict__ A2,
    const unsigned short* __restrict__ Wt, const float* __restrict__ bias,
    float* __restrict__ Cf, unsigned short* __restrict__ Cb,
    unsigned short* __restrict__ Oq, unsigned char* __restrict__ Ok, unsigned char* __restrict__ Ov,
    int M, int K1, int K, int Ncol, int ldb)
{
  __shared__ unsigned short As[128 * 64];
  __shared__ unsigned short Bs[128 * 64];
  const int tid = threadIdx.x;
  const int lane = tid & 63;
  const int wid = tid >> 6;
  const int bm = blockIdx.x * 128;
  const int bn = blockIdx.y * 128;
  const int wr = (wid >> 1) << 6;
  const int wc = (wid & 1) << 6;
  const int l15 = lane & 15, lhi = lane >> 4;
  const int srow = lane >> 3;
  const int scol = (lane & 7) << 3;

  f32x4 acc[4][4];
  #pragma unroll
  for (int i = 0; i < 4; ++i)
    #pragma unroll
    for (int j = 0; j < 4; ++j) acc[i][j] = (f32x4){0.f, 0.f, 0.f, 0.f};

  for (int k0 = 0; k0 < K; k0 += 64) {
    const unsigned short* Ab;
    int ks;
    if (k0 < K1) { Ab = A1; ks = k0; } else { Ab = A2; ks = k0 - K1; }
    #pragma unroll
    for (int t = 0; t < 4; ++t) {
      int qi = wid * 4 + t;
      const unsigned short* ga = Ab + (size_t)(bm + qi * 8 + srow) * 256 + ks + scol;
      __builtin_amdgcn_global_load_lds(
          (const __attribute__((address_space(1))) void*)ga,
          (__attribute__((address_space(3))) void*)&As[qi * 512], 16, 0, 0);
      const unsigned short* gb = Wt + (size_t)(bn + qi * 8 + srow) * ldb + k0 + scol;
      __builtin_amdgcn_global_load_lds(
          (const __attribute__((address_space(1))) void*)gb,
          (__attribute__((address_space(3))) void*)&Bs[qi * 512], 16, 0, 0);
    }
    __syncthreads();
    #pragma unroll
    for (int kk = 0; kk < 64; kk += 32) {
      bf16x8 af[4], bfr[4];
      #pragma unroll
      for (int mi = 0; mi < 4; ++mi)
        af[mi] = *(const bf16x8*)&As[(wr + mi * 16 + l15) * 64 + kk + lhi * 8];
      #pragma unroll
      for (int ni = 0; ni < 4; ++ni)
        bfr[ni] = *(const bf16x8*)&Bs[(wc + ni * 16 + l15) * 64 + kk + lhi * 8];
      #pragma unroll
      for (int mi = 0; mi < 4; ++mi)
        #pragma unroll
        for (int ni = 0; ni < 4; ++ni)
          acc[mi][ni] = __builtin_amdgcn_mfma_f32_16x16x32_bf16(af[mi], bfr[ni], acc[mi][ni], 0, 0, 0);
    }
    __syncthreads();
  }

  #pragma unroll
  for (int ni = 0; ni < 4; ++ni) {
    int gc = bn + wc + ni * 16 + l15;
    float bb = bias[gc];
    int h = 0, tq = 0;
    if (EPI == 3) { h = gc / 96; tq = gc - h * 96; }
    #pragma unroll
    for (int mi = 0; mi < 4; ++mi) {
      #pragma unroll
      for (int i = 0; i < 4; ++i) {
        int gr = bm + wr + mi * 16 + (lhi << 2) + i;
        if (gr >= M) continue;
        float val = acc[mi][ni][i] + bb;
        if (EPI == 0) {
          Cf[(size_t)gr * Ncol + gc] = val;
        } else if (EPI == 1) {
          Cb[(size_t)gr * Ncol + gc] = f2bf(val);
        } else if (EPI == 2) {
          val = 0.5f * val * (1.0f + erff(val * 0.70710678118654752f));
          Cb[(size_t)gr * Ncol + gc] = f2bf(val);
        } else {
          if (tq < HDIM)          Oq[(size_t)gr * NDIM + h * HDIM + tq] = f2bf(val);
          else if (tq < 2 * HDIM) Ok[(size_t)gr * NDIM + h * HDIM + (tq - HDIM)] = f2e4m3(val);
          else                    Ov[(size_t)gr * NDIM + h * HDIM + (tq - 2 * HDIM)] = f2e4m3(val);
        }
      }
    }
  }
}

extern "C" void kernel_launch(void* const* d_in, const int* in_sizes, int n_in,
                              void* d_out, int out_size, void* d_ws, size_t ws_size,
                              hipStream_t stream) {
  (void)n_in; (void)out_size; (void)ws_size;
  const float* x    = (const float*)d_in[0];
  const int*   src  = (const int*)d_in[1];
  const int*   dst  = (const int*)d_in[2];
  const float* Wqkv = (const float*)d_in[3];
  const float* bqkv = (const float*)d_in[4];
  const float* Wout = (const float*)d_in[5];
  const float* bout = (const float*)d_in[6];
  const float* W1   = (const float*)d_in[7];
  const float* b1   = (const float*)d_in[8];
  const float* W2   = (const float*)d_in[9];
  const float* b2   = (const float*)d_in[10];
  float* out = (float*)d_out;

  const int N = in_sizes[0] / NDIM;   // 50000
  const int E = in_sizes[1];          // 800000
  const int Mp = (N + 127) & ~127;    // 50048
  const int nb = (N + SCB - 1) / SCB; // 98

  char* ws = (char*)d_ws;
  size_t off = 0;
  auto alloc = [&](size_t bytes) -> char* {
    char* p = ws + off;
    off += (bytes + 255) & ~(size_t)255;
    return p;
  };
  unsigned short* xb   = (unsigned short*)alloc((size_t)Mp * NDIM * 2);
  unsigned short* Q    = (unsigned short*)alloc((size_t)Mp * NDIM * 2);
  unsigned short* Kb   = (unsigned short*)alloc((size_t)Mp * NDIM * 2);
  unsigned short* Vb   = (unsigned short*)alloc((size_t)Mp * NDIM * 2);
  unsigned short* wqkvt = (unsigned short*)alloc((size_t)768 * 256 * 2);
  unsigned short* woutt = (unsigned short*)alloc((size_t)256 * 256 * 2);
  unsigned short* w1t   = (unsigned short*)alloc((size_t)256 * 512 * 2);
  unsigned short* w2t   = (unsigned short*)alloc((size_t)256 * 256 * 2);
  int* deg    = (int*)alloc((size_t)N * 4);
  int* offs   = (int*)alloc((size_t)(N + 1) * 4);
  int* cursor = (int*)alloc((size_t)N * 4);
  int* ssrc   = (int*)alloc((size_t)E * 4);
  int* bsum   = (int*)alloc((size_t)nb * 4);

  unsigned char* K8 = (unsigned char*)Kb;   // fp8 K lives in Kb's footprint
  unsigned char* V8 = (unsigned char*)Vb;   // fp8 V lives in Vb's footprint
  unsigned short* agg    = Q;    // attn writes in place over Q
  unsigned short* aggout = Kb;   // dead after attn
  unsigned short* h1     = Vb;   // dead after attn

  // input/weight prep
  xconv_k<<<(N * NDIM / 8 + 255) / 256, 256, 0, stream>>>(x, xb, N * NDIM / 8);
  wconv_k<<<(256 * 768 + 255) / 256, 256, 0, stream>>>(Wqkv, wqkvt, 256, 768);
  wconv_k<<<(256 * 256 + 255) / 256, 256, 0, stream>>>(Wout, woutt, 256, 256);
  wconv_k<<<(512 * 256 + 255) / 256, 256, 0, stream>>>(W1, w1t, 512, 256);
  wconv_k<<<(256 * 256 + 255) / 256, 256, 0, stream>>>(W2, w2t, 256, 256);

  // CSR build (parallel scan)
  hipMemsetAsync(deg, 0, (size_t)N * 4, stream);
  hist_k<<<(E + 255) / 256, 256, 0, stream>>>(dst, deg, E);
  bsum_k<<<nb, SCB, 0, stream>>>(deg, bsum, N);
  bscan_k<<<1, 128, 0, stream>>>(bsum, nb);
  offs_k<<<nb, SCB, 0, stream>>>(deg, bsum, offs, N);
  hipMemcpyAsync(cursor, offs, (size_t)N * 4, hipMemcpyDeviceToDevice, stream);
  scatter_k<<<(E + 255) / 256, 256, 0, stream>>>(src, dst, cursor, ssrc, E);

  const int mt = Mp / 128;   // 391

  // QKV projection -> Q (bf16), K8/V8 (fp8)
  mgemm_k<3><<<dim3(mt, 6), 256, 0, stream>>>(
      xb, nullptr, wqkvt, bqkv, nullptr, nullptr, Q, K8, V8, N, 256, 256, 768, 256);

  // edge-softmax aggregation (agg == Q in place)
  attn_k<<<(N + 3) / 4, 256, 0, stream>>>(Q, K8, V8, offs, ssrc, agg, N);

  // agg @ Wout + bout -> aggout (bf16)
  mgemm_k<1><<<dim3(mt, 2), 256, 0, stream>>>(
      agg, nullptr, woutt, bout, nullptr, aggout, nullptr, nullptr, nullptr, N, 256, 256, 256, 256);

  // gelu([xb | aggout] @ W1 + b1) -> h1 (bf16)
  mgemm_k<2><<<dim3(mt, 2), 256, 0, stream>>>(
      xb, aggout, w1t, b1, nullptr, h1, nullptr, nullptr, nullptr, N, 256, 512, 256, 512);

  // h1 @ W2 + b2 -> out (fp32)
  mgemm_k<0><<<dim3(mt, 2), 256, 0, stream>>>(
      h1, nullptr, w2t, b2, out, nullptr, nullptr, nullptr, nullptr, N, 256, 256, 256, 256);
}

// Round 6
// 318.920 us; speedup vs baseline: 3.0747x; 1.1732x over previous
//
#include <hip/hip_runtime.h>
#include <hip/hip_bf16.h>
#include <math.h>

#define NDIM 256
#define HDIM 32
#define SCB 512

typedef __attribute__((ext_vector_type(8))) short bf16x8;
typedef __attribute__((ext_vector_type(4))) float f32x4;
typedef __attribute__((ext_vector_type(2))) float f32x2;

// ---------- bf16 helpers ----------
__device__ inline float bf2f(unsigned short u) {
  union { unsigned int i; float f; } c; c.i = ((unsigned int)u) << 16; return c.f;
}
__device__ inline unsigned short f2bf(float f) {
  union { float f; unsigned int i; } c; c.f = f;
  unsigned int x = c.i;
  unsigned int lsb = (x >> 16) & 1u;
  x += 0x7fffu + lsb;
  return (unsigned short)(x >> 16);
}
__device__ inline float4 ldbf4(const unsigned short* p) {
  unsigned long long raw = *(const unsigned long long*)p;
  float4 f;
  f.x = bf2f((unsigned short)(raw));
  f.y = bf2f((unsigned short)(raw >> 16));
  f.z = bf2f((unsigned short)(raw >> 32));
  f.w = bf2f((unsigned short)(raw >> 48));
  return f;
}
__device__ inline void stbf4(unsigned short* p, float4 v) {
  unsigned long long raw = (unsigned long long)f2bf(v.x)
                         | ((unsigned long long)f2bf(v.y) << 16)
                         | ((unsigned long long)f2bf(v.z) << 32)
                         | ((unsigned long long)f2bf(v.w) << 48);
  *(unsigned long long*)p = raw;
}

// ---------- fp8 e4m3 helpers (HW cvt with manual fallback) ----------
__device__ inline unsigned char f2e4m3(float v) {
#if __has_builtin(__builtin_amdgcn_cvt_pk_fp8_f32)
  return (unsigned char)(__builtin_amdgcn_cvt_pk_fp8_f32(v, v, 0, false) & 0xff);
#else
  union { float f; unsigned int u; } c; c.f = v;
  unsigned char s = (unsigned char)((c.u >> 24) & 0x80);
  float a = fabsf(v);
  if (!(a < 448.f)) return (unsigned char)(s | 0x7e);
  if (a < 0.0009765625f) return s;
  int e = (int)((c.u >> 23) & 0xff) - 127;
  if (e < -6) {
    int q = (int)rintf(ldexpf(a, 9));
    if (q >= 8) return (unsigned char)(s | 0x08);
    return (unsigned char)(s | q);
  }
  int q = (int)rintf(ldexpf(a, 3 - e));
  if (q == 16) { e++; q = 8; }
  if (e > 8) return (unsigned char)(s | 0x7e);
  return (unsigned char)(s | ((e + 7) << 3) | (q - 8));
#endif
}
template<bool HI>
__device__ inline f32x2 e4m3pk(unsigned int w) {
#if __has_builtin(__builtin_amdgcn_cvt_pk_f32_fp8)
  return __builtin_amdgcn_cvt_pk_f32_fp8((int)w, HI);
#else
  unsigned int h = HI ? (w >> 16) : w;
  f32x2 r;
  #pragma unroll
  for (int j = 0; j < 2; ++j) {
    unsigned char b = (unsigned char)(h >> (8 * j));
    int e = (b >> 3) & 0xf, mm = b & 7;
    float val = e ? ldexpf((float)(8 + mm), e - 10) : ldexpf((float)mm, -9);
    r[j] = (b & 0x80) ? -val : val;
  }
  return r;
#endif
}

// ---------- fp32 -> bf16 bulk convert ----------
__global__ void xconv_k(const float* __restrict__ x, unsigned short* __restrict__ xb, int n8) {
  int i = blockIdx.x * 256 + threadIdx.x;
  if (i >= n8) return;
  const float* p = x + (size_t)i * 8;
  float4 a = *(const float4*)p;
  float4 b = *(const float4*)(p + 4);
  unsigned long long lo = (unsigned long long)f2bf(a.x) | ((unsigned long long)f2bf(a.y) << 16)
                        | ((unsigned long long)f2bf(a.z) << 32) | ((unsigned long long)f2bf(a.w) << 48);
  unsigned long long hi = (unsigned long long)f2bf(b.x) | ((unsigned long long)f2bf(b.y) << 16)
                        | ((unsigned long long)f2bf(b.z) << 32) | ((unsigned long long)f2bf(b.w) << 48);
  unsigned long long* d = (unsigned long long*)(xb + (size_t)i * 8);
  d[0] = lo; d[1] = hi;
}

// ---------- weight transpose + bf16 convert: Wt[n][k] = bf16(W[k][n]) ----------
__global__ void wconv_k(const float* __restrict__ W, unsigned short* __restrict__ Wt,
                        int K, int Ncol) {
  int idx = blockIdx.x * 256 + threadIdx.x;
  if (idx < K * Ncol) {
    int n = idx / K;
    int k = idx - n * K;
    Wt[idx] = f2bf(W[(size_t)k * Ncol + n]);
  }
}

// ---------- Wqkv transpose + bf16 + column permutation ----------
// output col j: j<256 -> q(h=j>>5,t=j&31); 256..511 -> k; 512..767 -> v
// orig col = h*96 + seg*32 + t
__global__ void wconvqkv_k(const float* __restrict__ W, unsigned short* __restrict__ Wt) {
  int idx = blockIdx.x * 256 + threadIdx.x;   // idx over 768*256
  if (idx >= 768 * 256) return;
  int j = idx >> 8;          // out col 0..767
  int k = idx & 255;         // k index
  int seg = j >> 8;
  int jj = j & 255;
  int h = jj >> 5, t = jj & 31;
  int orig = h * 96 + seg * 32 + t;
  Wt[(size_t)j * 256 + k] = f2bf(W[(size_t)k * 768 + orig]);
}

// ---------- CSR build ----------
__global__ void hist_k(const int* __restrict__ dst, int* __restrict__ deg, int E) {
  int e = blockIdx.x * 256 + threadIdx.x;
  if (e < E) atomicAdd(&deg[dst[e]], 1);
}

__global__ __launch_bounds__(SCB) void bsum_k(const int* __restrict__ deg, int* __restrict__ bsum, int n) {
  int tid = threadIdx.x;
  int i = blockIdx.x * SCB + tid;
  int v = (i < n) ? deg[i] : 0;
  #pragma unroll
  for (int d = 1; d < 64; d <<= 1) v += __shfl_xor(v, d);
  __shared__ int wsum[8];
  if ((tid & 63) == 0) wsum[tid >> 6] = v;
  __syncthreads();
  if (tid == 0) {
    int s = 0;
    #pragma unroll
    for (int j = 0; j < 8; ++j) s += wsum[j];
    bsum[blockIdx.x] = s;
  }
}

__global__ __launch_bounds__(128) void bscan_k(int* __restrict__ bsum, int nb) {
  __shared__ int tmp[128];
  int tid = threadIdx.x;
  int v = (tid < nb) ? bsum[tid] : 0;
  tmp[tid] = v;
  __syncthreads();
  for (int d = 1; d < 128; d <<= 1) {
    int t = (tid >= d) ? tmp[tid - d] : 0;
    __syncthreads();
    tmp[tid] += t;
    __syncthreads();
  }
  if (tid < nb) bsum[tid] = tmp[tid];
}

__global__ __launch_bounds__(SCB) void offs_k(const int* __restrict__ deg, const int* __restrict__ bsum,
                                              int* __restrict__ offs, int n) {
  int tid = threadIdx.x, lane = tid & 63, wid = tid >> 6;
  int b = blockIdx.x;
  int i = b * SCB + tid;
  int v = (i < n) ? deg[i] : 0;
  int incl = v;
  #pragma unroll
  for (int d = 1; d < 64; d <<= 1) { int t = __shfl_up(incl, d); if (lane >= d) incl += t; }
  __shared__ int wsum[8];
  if (lane == 63) wsum[wid] = incl;
  __syncthreads();
  if (tid < 8) {
    int s = wsum[tid];
    #pragma unroll
    for (int d = 1; d < 8; d <<= 1) { int t = __shfl_up(s, d); if (tid >= d) s += t; }
    wsum[tid] = s;
  }
  __syncthreads();
  int base = (b > 0 ? bsum[b - 1] : 0) + (wid > 0 ? wsum[wid - 1] : 0);
  if (i < n) offs[i] = base + incl - v;
  if (i == n - 1) offs[n] = base + incl;
}

__global__ void scatter_k(const int* __restrict__ src, const int* __restrict__ dst,
                          int* __restrict__ cursor, int* __restrict__ ssrc, int E) {
  int e = blockIdx.x * 256 + threadIdx.x;
  if (e < E) {
    int p = atomicAdd(&cursor[dst[e]], 1);
    ssrc[p] = src[e];
  }
}

// ---------- per-node online-softmax attention, fp8 K/V, 8x unrolled ----------
__global__ __launch_bounds__(256) void attn_k(
    const unsigned short* Q,
    const unsigned char* __restrict__ K8,
    const unsigned char* __restrict__ V8,
    const int* __restrict__ offs,
    const int* __restrict__ ssrc,
    unsigned short* agg, int N)
{
  int n = blockIdx.x * 4 + (threadIdx.x >> 6);
  if (n >= N) return;
  int lane = threadIdx.x & 63;
  int col = lane << 2;
  const float scale = 0.17677669529663689f;
  float4 q4 = ldbf4(Q + (size_t)n * NDIM + col);
  q4.x *= scale; q4.y *= scale; q4.z *= scale; q4.w *= scale;
  int e0 = offs[n], e1 = offs[n + 1];
  float m = -INFINITY, den = 0.f;
  float ax = 0.f, ay = 0.f, az = 0.f, aw = 0.f;
  int e = e0;
  for (; e + 8 <= e1; e += 8) {
    unsigned int kw[8], vw[8];
    #pragma unroll
    for (int j = 0; j < 8; ++j) {
      int s = ssrc[e + j];
      kw[j] = *(const unsigned int*)(K8 + (size_t)s * NDIM + col);
      vw[j] = *(const unsigned int*)(V8 + (size_t)s * NDIM + col);
    }
    float d[8];
    #pragma unroll
    for (int j = 0; j < 8; ++j) {
      f32x2 k01 = e4m3pk<false>(kw[j]);
      f32x2 k23 = e4m3pk<true>(kw[j]);
      d[j] = q4.x * k01[0] + q4.y * k01[1] + q4.z * k23[0] + q4.w * k23[1];
    }
    #pragma unroll
    for (int j = 0; j < 8; ++j) {
      d[j] += __shfl_xor(d[j], 1);
      d[j] += __shfl_xor(d[j], 2);
      d[j] += __shfl_xor(d[j], 4);
    }
    float mx = d[0];
    #pragma unroll
    for (int j = 1; j < 8; ++j) mx = fmaxf(mx, d[j]);
    float nm = fmaxf(m, mx);
    float fr = __expf(m - nm);
    float p[8], ps = 0.f;
    #pragma unroll
    for (int j = 0; j < 8; ++j) { p[j] = __expf(d[j] - nm); ps += p[j]; }
    den = den * fr + ps;
    ax *= fr; ay *= fr; az *= fr; aw *= fr;
    #pragma unroll
    for (int j = 0; j < 8; ++j) {
      f32x2 v01 = e4m3pk<false>(vw[j]);
      f32x2 v23 = e4m3pk<true>(vw[j]);
      ax += p[j] * v01[0]; ay += p[j] * v01[1];
      az += p[j] * v23[0]; aw += p[j] * v23[1];
    }
    m = nm;
  }
  for (; e < e1; ++e) {
    int s = ssrc[e];
    unsigned int kw = *(const unsigned int*)(K8 + (size_t)s * NDIM + col);
    unsigned int vw = *(const unsigned int*)(V8 + (size_t)s * NDIM + col);
    f32x2 k01 = e4m3pk<false>(kw);
    f32x2 k23 = e4m3pk<true>(kw);
    float d = q4.x * k01[0] + q4.y * k01[1] + q4.z * k23[0] + q4.w * k23[1];
    d += __shfl_xor(d, 1);
    d += __shfl_xor(d, 2);
    d += __shfl_xor(d, 4);
    float nm = fmaxf(m, d);
    float fr = __expf(m - nm);
    float p = __expf(d - nm);
    den = den * fr + p;
    f32x2 v01 = e4m3pk<false>(vw);
    f32x2 v23 = e4m3pk<true>(vw);
    ax = ax * fr + p * v01[0]; ay = ay * fr + p * v01[1];
    az = az * fr + p * v23[0]; aw = aw * fr + p * v23[1];
    m = nm;
  }
  float inv = (den > 0.f) ? 1.f / den : 0.f;
  stbf4(agg + (size_t)n * NDIM + col, make_float4(ax * inv, ay * inv, az * inv, aw * inv));
}

// ---------- MFMA GEMM: m97 structure + T2 XOR-swizzle (pre-swizzled source) + XCD swizzle ----------
// 1D grid nwg = mt*nct; bijective XCD chunking, col-tile fastest within chunk.
// EPI: 0 = fp32, 1 = bf16, 2 = gelu+bf16, 3 = qkv split (cols pre-permuted: 0-255 Q bf16, 256-511 K fp8, 512-767 V fp8)
template<int EPI>
__global__ __launch_bounds__(256, 4) void mgemm_k(
    const unsigned short* __restrict__ A1, const unsigned short* __restrict__ A2,
    const unsigned short* __restrict__ Wt, const float* __restrict__ bias,
    float* __restrict__ Cf, unsigned short* __restrict__ Cb,
    unsigned short* __restrict__ Oq, unsigned char* __restrict__ Ok, unsigned char* __restrict__ Ov,
    int M, int K1, int K, int Ncol, int ldb, int nct)
{
  __shared__ unsigned short As[128 * 64];
  __shared__ unsigned short Bs[128 * 64];
  const int tid = threadIdx.x;
  const int lane = tid & 63;
  const int wid = tid >> 6;

  // XCD-aware bijective block swizzle (m204), col-tile fastest within an XCD chunk
  const int nwg = gridDim.x;
  const int q8 = nwg >> 3, r8 = nwg & 7;
  const int xcd = blockIdx.x & 7, idx8 = blockIdx.x >> 3;
  const int swz = (xcd < r8 ? xcd * (q8 + 1) : r8 * (q8 + 1) + (xcd - r8) * q8) + idx8;
  const int bmt = swz / nct;
  const int bnt = swz - bmt * nct;
  const int bm = bmt * 128;
  const int bn = bnt * 128;

  const int wr = (wid >> 1) << 6;
  const int wc = (wid & 1) << 6;
  const int l15 = lane & 15, lhi = lane >> 4;
  const int srow = lane >> 3;                                  // 0..7
  const int ssl = (((lane & 7) ^ (lane >> 3)) << 3);           // inverse-swizzled 16B slot (elements)

  f32x4 acc[4][4];
  #pragma unroll
  for (int i = 0; i < 4; ++i)
    #pragma unroll
    for (int j = 0; j < 4; ++j) acc[i][j] = (f32x4){0.f, 0.f, 0.f, 0.f};

  for (int k0 = 0; k0 < K; k0 += 64) {
    const unsigned short* Ab;
    int ks;
    if (k0 < K1) { Ab = A1; ks = k0; } else { Ab = A2; ks = k0 - K1; }
    #pragma unroll
    for (int t = 0; t < 4; ++t) {
      int qi = wid * 4 + t;
      const unsigned short* ga = Ab + (size_t)(bm + qi * 8 + srow) * 256 + ks + ssl;
      __builtin_amdgcn_global_load_lds(
          (const __attribute__((address_space(1))) void*)ga,
          (__attribute__((address_space(3))) void*)&As[qi * 512], 16, 0, 0);
      const unsigned short* gb = Wt + (size_t)(bn + qi * 8 + srow) * ldb + k0 + ssl;
      __builtin_amdgcn_global_load_lds(
          (const __attribute__((address_space(1))) void*)gb,
          (__attribute__((address_space(3))) void*)&Bs[qi * 512], 16, 0, 0);
    }
    __syncthreads();
    #pragma unroll
    for (int kk = 0; kk < 64; kk += 32) {
      bf16x8 af[4], bfr[4];
      #pragma unroll
      for (int mi = 0; mi < 4; ++mi) {
        int rA = wr + mi * 16 + l15;
        af[mi] = *(const bf16x8*)&As[rA * 64 + ((((kk >> 3) + lhi) ^ (rA & 7)) << 3)];
      }
      #pragma unroll
      for (int ni = 0; ni < 4; ++ni) {
        int rB = wc + ni * 16 + l15;
        bfr[ni] = *(const bf16x8*)&Bs[rB * 64 + ((((kk >> 3) + lhi) ^ (rB & 7)) << 3)];
      }
      #pragma unroll
      for (int mi = 0; mi < 4; ++mi)
        #pragma unroll
        for (int ni = 0; ni < 4; ++ni)
          acc[mi][ni] = __builtin_amdgcn_mfma_f32_16x16x32_bf16(af[mi], bfr[ni], acc[mi][ni], 0, 0, 0);
    }
    __syncthreads();
  }

  // epilogue: lane holds C[bm+wr+mi*16+lhi*4+i][bn+wc+ni*16+l15]
  #pragma unroll
  for (int ni = 0; ni < 4; ++ni) {
    int gc = bn + wc + ni * 16 + l15;
    int seg = 0, jj = gc;
    float bb;
    if (EPI == 3) {
      seg = gc >> 8; jj = gc & 255;
      int h = jj >> 5, t = jj & 31;
      bb = bias[h * 96 + seg * 32 + t];
    } else {
      bb = bias[gc];
    }
    #pragma unroll
    for (int mi = 0; mi < 4; ++mi) {
      #pragma unroll
      for (int i = 0; i < 4; ++i) {
        int gr = bm + wr + mi * 16 + (lhi << 2) + i;
        if (gr >= M) continue;
        float val = acc[mi][ni][i] + bb;
        if (EPI == 0) {
          Cf[(size_t)gr * Ncol + gc] = val;
        } else if (EPI == 1) {
          Cb[(size_t)gr * Ncol + gc] = f2bf(val);
        } else if (EPI == 2) {
          val = 0.5f * val * (1.0f + erff(val * 0.70710678118654752f));
          Cb[(size_t)gr * Ncol + gc] = f2bf(val);
        } else {
          if (seg == 0)      Oq[(size_t)gr * NDIM + jj] = f2bf(val);
          else if (seg == 1) Ok[(size_t)gr * NDIM + jj] = f2e4m3(val);
          else               Ov[(size_t)gr * NDIM + jj] = f2e4m3(val);
        }
      }
    }
  }
}

extern "C" void kernel_launch(void* const* d_in, const int* in_sizes, int n_in,
                              void* d_out, int out_size, void* d_ws, size_t ws_size,
                              hipStream_t stream) {
  (void)n_in; (void)out_size; (void)ws_size;
  const float* x    = (const float*)d_in[0];
  const int*   src  = (const int*)d_in[1];
  const int*   dst  = (const int*)d_in[2];
  const float* Wqkv = (const float*)d_in[3];
  const float* bqkv = (const float*)d_in[4];
  const float* Wout = (const float*)d_in[5];
  const float* bout = (const float*)d_in[6];
  const float* W1   = (const float*)d_in[7];
  const float* b1   = (const float*)d_in[8];
  const float* W2   = (const float*)d_in[9];
  const float* b2   = (const float*)d_in[10];
  float* out = (float*)d_out;

  const int N = in_sizes[0] / NDIM;   // 50000
  const int E = in_sizes[1];          // 800000
  const int Mp = (N + 127) & ~127;    // 50048
  const int nb = (N + SCB - 1) / SCB; // 98

  char* ws = (char*)d_ws;
  size_t off = 0;
  auto alloc = [&](size_t bytes) -> char* {
    char* p = ws + off;
    off += (bytes + 255) & ~(size_t)255;
    return p;
  };
  unsigned short* xb   = (unsigned short*)alloc((size_t)Mp * NDIM * 2);
  unsigned short* Q    = (unsigned short*)alloc((size_t)Mp * NDIM * 2);
  unsigned short* Kb   = (unsigned short*)alloc((size_t)Mp * NDIM * 2);
  unsigned short* Vb   = (unsigned short*)alloc((size_t)Mp * NDIM * 2);
  unsigned short* wqkvt = (unsigned short*)alloc((size_t)768 * 256 * 2);
  unsigned short* woutt = (unsigned short*)alloc((size_t)256 * 256 * 2);
  unsigned short* w1t   = (unsigned short*)alloc((size_t)256 * 512 * 2);
  unsigned short* w2t   = (unsigned short*)alloc((size_t)256 * 256 * 2);
  int* deg    = (int*)alloc((size_t)N * 4);
  int* offs   = (int*)alloc((size_t)(N + 1) * 4);
  int* cursor = (int*)alloc((size_t)N * 4);
  int* ssrc   = (int*)alloc((size_t)E * 4);
  int* bsum   = (int*)alloc((size_t)nb * 4);

  unsigned char* K8 = (unsigned char*)Kb;
  unsigned char* V8 = (unsigned char*)Vb;
  unsigned short* agg    = Q;    // attn writes in place over Q
  unsigned short* aggout = Kb;   // dead after attn
  unsigned short* h1     = Vb;   // dead after attn

  // input/weight prep
  xconv_k<<<(N * NDIM / 8 + 255) / 256, 256, 0, stream>>>(x, xb, N * NDIM / 8);
  wconvqkv_k<<<(768 * 256 + 255) / 256, 256, 0, stream>>>(Wqkv, wqkvt);
  wconv_k<<<(256 * 256 + 255) / 256, 256, 0, stream>>>(Wout, woutt, 256, 256);
  wconv_k<<<(512 * 256 + 255) / 256, 256, 0, stream>>>(W1, w1t, 512, 256);
  wconv_k<<<(256 * 256 + 255) / 256, 256, 0, stream>>>(W2, w2t, 256, 256);

  // CSR build (parallel scan)
  hipMemsetAsync(deg, 0, (size_t)N * 4, stream);
  hist_k<<<(E + 255) / 256, 256, 0, stream>>>(dst, deg, E);
  bsum_k<<<nb, SCB, 0, stream>>>(deg, bsum, N);
  bscan_k<<<1, 128, 0, stream>>>(bsum, nb);
  offs_k<<<nb, SCB, 0, stream>>>(deg, bsum, offs, N);
  hipMemcpyAsync(cursor, offs, (size_t)N * 4, hipMemcpyDeviceToDevice, stream);
  scatter_k<<<(E + 255) / 256, 256, 0, stream>>>(src, dst, cursor, ssrc, E);

  const int mt = Mp / 128;   // 391

  // QKV projection -> Q (bf16), K8/V8 (fp8); wqkvt is column-permuted
  mgemm_k<3><<<mt * 6, 256, 0, stream>>>(
      xb, nullptr, wqkvt, bqkv, nullptr, nullptr, Q, K8, V8, N, 256, 256, 768, 256, 6);

  // edge-softmax aggregation (agg == Q in place)
  attn_k<<<(N + 3) / 4, 256, 0, stream>>>(Q, K8, V8, offs, ssrc, agg, N);

  // agg @ Wout + bout -> aggout (bf16)
  mgemm_k<1><<<mt * 2, 256, 0, stream>>>(
      agg, nullptr, woutt, bout, nullptr, aggout, nullptr, nullptr, nullptr, N, 256, 256, 256, 256, 2);

  // gelu([xb | aggout] @ W1 + b1) -> h1 (bf16)
  mgemm_k<2><<<mt * 2, 256, 0, stream>>>(
      xb, aggout, w1t, b1, nullptr, h1, nullptr, nullptr, nullptr, N, 256, 512, 256, 512, 2);

  // h1 @ W2 + b2 -> out (fp32)
  mgemm_k<0><<<mt * 2, 256, 0, stream>>>(
      h1, nullptr, w2t, b2, out, nullptr, nullptr, nullptr, nullptr, N, 256, 256, 256, 256, 2);
}

// Round 7
// 301.964 us; speedup vs baseline: 3.2474x; 1.0562x over previous
//
#include <hip/hip_runtime.h>
#include <hip/hip_bf16.h>
#include <math.h>

#define NDIM 256
#define HDIM 32
#define SCB 512

typedef __attribute__((ext_vector_type(8))) short bf16x8;
typedef __attribute__((ext_vector_type(4))) float f32x4;
typedef __attribute__((ext_vector_type(2))) float f32x2;
typedef unsigned long long ull;

// ---------- bf16 helpers ----------
__device__ inline float bf2f(unsigned short u) {
  union { unsigned int i; float f; } c; c.i = ((unsigned int)u) << 16; return c.f;
}
__device__ inline unsigned short f2bf(float f) {
  union { float f; unsigned int i; } c; c.f = f;
  unsigned int x = c.i;
  unsigned int lsb = (x >> 16) & 1u;
  x += 0x7fffu + lsb;
  return (unsigned short)(x >> 16);
}
__device__ inline float4 ldbf4(const unsigned short* p) {
  ull raw = *(const ull*)p;
  float4 f;
  f.x = bf2f((unsigned short)(raw));
  f.y = bf2f((unsigned short)(raw >> 16));
  f.z = bf2f((unsigned short)(raw >> 32));
  f.w = bf2f((unsigned short)(raw >> 48));
  return f;
}
__device__ inline void stbf4(unsigned short* p, float4 v) {
  ull raw = (ull)f2bf(v.x) | ((ull)f2bf(v.y) << 16)
          | ((ull)f2bf(v.z) << 32) | ((ull)f2bf(v.w) << 48);
  *(ull*)p = raw;
}
__device__ inline ull pk4_bf16(float v0, float v1, float v2, float v3) {
  return (ull)f2bf(v0) | ((ull)f2bf(v1) << 16) | ((ull)f2bf(v2) << 32) | ((ull)f2bf(v3) << 48);
}

// ---------- fp8 e4m3 helpers ----------
__device__ inline unsigned char f2e4m3(float v) {
#if __has_builtin(__builtin_amdgcn_cvt_pk_fp8_f32)
  return (unsigned char)(__builtin_amdgcn_cvt_pk_fp8_f32(v, v, 0, false) & 0xff);
#else
  union { float f; unsigned int u; } c; c.f = v;
  unsigned char s = (unsigned char)((c.u >> 24) & 0x80);
  float a = fabsf(v);
  if (!(a < 448.f)) return (unsigned char)(s | 0x7e);
  if (a < 0.0009765625f) return s;
  int e = (int)((c.u >> 23) & 0xff) - 127;
  if (e < -6) {
    int q = (int)rintf(ldexpf(a, 9));
    if (q >= 8) return (unsigned char)(s | 0x08);
    return (unsigned char)(s | q);
  }
  int q = (int)rintf(ldexpf(a, 3 - e));
  if (q == 16) { e++; q = 8; }
  if (e > 8) return (unsigned char)(s | 0x7e);
  return (unsigned char)(s | ((e + 7) << 3) | (q - 8));
#endif
}
__device__ inline unsigned int pk4_e4m3(float v0, float v1, float v2, float v3) {
#if __has_builtin(__builtin_amdgcn_cvt_pk_fp8_f32)
  int w = __builtin_amdgcn_cvt_pk_fp8_f32(v0, v1, 0, false);
  w = __builtin_amdgcn_cvt_pk_fp8_f32(v2, v3, w, true);
  return (unsigned int)w;
#else
  return (unsigned int)f2e4m3(v0) | ((unsigned int)f2e4m3(v1) << 8)
       | ((unsigned int)f2e4m3(v2) << 16) | ((unsigned int)f2e4m3(v3) << 24);
#endif
}
template<bool HI>
__device__ inline f32x2 e4m3pk(unsigned int w) {
#if __has_builtin(__builtin_amdgcn_cvt_pk_f32_fp8)
  return __builtin_amdgcn_cvt_pk_f32_fp8((int)w, HI);
#else
  unsigned int h = HI ? (w >> 16) : w;
  f32x2 r;
  #pragma unroll
  for (int j = 0; j < 2; ++j) {
    unsigned char b = (unsigned char)(h >> (8 * j));
    int e = (b >> 3) & 0xf, mm = b & 7;
    float val = e ? ldexpf((float)(8 + mm), e - 10) : ldexpf((float)mm, -9);
    r[j] = (b & 0x80) ? -val : val;
  }
  return r;
#endif
}

// ---------- fp32 -> bf16 bulk convert ----------
__global__ void xconv_k(const float* __restrict__ x, unsigned short* __restrict__ xb, int n8) {
  int i = blockIdx.x * 256 + threadIdx.x;
  if (i >= n8) return;
  const float* p = x + (size_t)i * 8;
  float4 a = *(const float4*)p;
  float4 b = *(const float4*)(p + 4);
  ull lo = (ull)f2bf(a.x) | ((ull)f2bf(a.y) << 16) | ((ull)f2bf(a.z) << 32) | ((ull)f2bf(a.w) << 48);
  ull hi = (ull)f2bf(b.x) | ((ull)f2bf(b.y) << 16) | ((ull)f2bf(b.z) << 32) | ((ull)f2bf(b.w) << 48);
  ull* d = (ull*)(xb + (size_t)i * 8);
  d[0] = lo; d[1] = hi;
}

// ---------- weight transpose + bf16: Wt[n][k] = bf16(W[k][n]) ----------
__global__ void wconv_k(const float* __restrict__ W, unsigned short* __restrict__ Wt,
                        int K, int Ncol) {
  int idx = blockIdx.x * 256 + threadIdx.x;
  if (idx < K * Ncol) {
    int n = idx / K;
    int k = idx - n * K;
    Wt[idx] = f2bf(W[(size_t)k * Ncol + n]);
  }
}

// ---------- Wqkv transpose + bf16 + column permutation ----------
__global__ void wconvqkv_k(const float* __restrict__ W, unsigned short* __restrict__ Wt) {
  int idx = blockIdx.x * 256 + threadIdx.x;   // over 768*256
  if (idx >= 768 * 256) return;
  int j = idx >> 8;          // out col 0..767
  int k = idx & 255;
  int seg = j >> 8;
  int jj = j & 255;
  int h = jj >> 5, t = jj & 31;
  int orig = h * 96 + seg * 32 + t;
  Wt[(size_t)j * 256 + k] = f2bf(W[(size_t)k * 768 + orig]);
}

// ---------- fused-FFN weight build ----------
// wf[n][k] (ld 512): k<256 -> bf16(W1[k][n]);  k=256+a -> bf16(sum_j Wout[a][j]*W1[256+j][n])
__global__ void wf1_k(const float* __restrict__ W1, unsigned short* __restrict__ wf) {
  int idx = blockIdx.x * 256 + threadIdx.x;   // over 256*256
  if (idx >= 256 * 256) return;
  int n = idx >> 8, k = idx & 255;
  wf[(size_t)n * 512 + k] = f2bf(W1[(size_t)k * 256 + n]);
}
__global__ void wfc_k(const float* __restrict__ Wout, const float* __restrict__ W1,
                      unsigned short* __restrict__ wf) {
  int idx = blockIdx.x * 256 + threadIdx.x;   // over 256*256
  if (idx >= 256 * 256) return;
  int n = idx >> 8, a = idx & 255;
  float s = 0.f;
  #pragma unroll 4
  for (int j = 0; j < 256; ++j)
    s += Wout[(size_t)a * 256 + j] * W1[(size_t)(256 + j) * 256 + n];
  wf[(size_t)n * 512 + 256 + a] = f2bf(s);
}
__global__ void bfc_k(const float* __restrict__ bout, const float* __restrict__ b1,
                      const float* __restrict__ W1, float* __restrict__ bc) {
  int n = threadIdx.x;
  float s = b1[n];
  for (int j = 0; j < 256; ++j)
    s += bout[j] * W1[(size_t)(256 + j) * 256 + n];
  bc[n] = s;
}

// ---------- CSR build ----------
__global__ void hist_k(const int* __restrict__ dst, int* __restrict__ deg, int E) {
  int e = blockIdx.x * 256 + threadIdx.x;
  if (e < E) atomicAdd(&deg[dst[e]], 1);
}

__global__ __launch_bounds__(SCB) void bsum_k(const int* __restrict__ deg, int* __restrict__ bsum, int n) {
  int tid = threadIdx.x;
  int i = blockIdx.x * SCB + tid;
  int v = (i < n) ? deg[i] : 0;
  #pragma unroll
  for (int d = 1; d < 64; d <<= 1) v += __shfl_xor(v, d);
  __shared__ int wsum[8];
  if ((tid & 63) == 0) wsum[tid >> 6] = v;
  __syncthreads();
  if (tid == 0) {
    int s = 0;
    #pragma unroll
    for (int j = 0; j < 8; ++j) s += wsum[j];
    bsum[blockIdx.x] = s;
  }
}

__global__ __launch_bounds__(128) void bscan_k(int* __restrict__ bsum, int nb) {
  __shared__ int tmp[128];
  int tid = threadIdx.x;
  int v = (tid < nb) ? bsum[tid] : 0;
  tmp[tid] = v;
  __syncthreads();
  for (int d = 1; d < 128; d <<= 1) {
    int t = (tid >= d) ? tmp[tid - d] : 0;
    __syncthreads();
    tmp[tid] += t;
    __syncthreads();
  }
  if (tid < nb) bsum[tid] = tmp[tid];
}

__global__ __launch_bounds__(SCB) void offs_k(const int* __restrict__ deg, const int* __restrict__ bsum,
                                              int* __restrict__ offs, int n) {
  int tid = threadIdx.x, lane = tid & 63, wid = tid >> 6;
  int b = blockIdx.x;
  int i = b * SCB + tid;
  int v = (i < n) ? deg[i] : 0;
  int incl = v;
  #pragma unroll
  for (int d = 1; d < 64; d <<= 1) { int t = __shfl_up(incl, d); if (lane >= d) incl += t; }
  __shared__ int wsum[8];
  if (lane == 63) wsum[wid] = incl;
  __syncthreads();
  if (tid < 8) {
    int s = wsum[tid];
    #pragma unroll
    for (int d = 1; d < 8; d <<= 1) { int t = __shfl_up(s, d); if (tid >= d) s += t; }
    wsum[tid] = s;
  }
  __syncthreads();
  int base = (b > 0 ? bsum[b - 1] : 0) + (wid > 0 ? wsum[wid - 1] : 0);
  if (i < n) offs[i] = base + incl - v;
  if (i == n - 1) offs[n] = base + incl;
}

__global__ void scatter_k(const int* __restrict__ src, const int* __restrict__ dst,
                          int* __restrict__ cursor, int* __restrict__ ssrc, int E) {
  int e = blockIdx.x * 256 + threadIdx.x;
  if (e < E) {
    int p = atomicAdd(&cursor[dst[e]], 1);
    ssrc[p] = src[e];
  }
}

// ---------- per-node softmax attention, fp8 K/V, fixed-shift (no max tracking) ----------
// scores bounded (|s| << 88): exp(s) safe; softmax is shift-invariant -> identical result.
// agg aliases Q (node n's Q row read only by node n's wave, before its write)
__global__ __launch_bounds__(256) void attn_k(
    const unsigned short* Q,
    const unsigned char* __restrict__ K8,
    const unsigned char* __restrict__ V8,
    const int* __restrict__ offs,
    const int* __restrict__ ssrc,
    unsigned short* agg, int N)
{
  int n = blockIdx.x * 4 + (threadIdx.x >> 6);
  if (n >= N) return;
  int lane = threadIdx.x & 63;
  int col = lane << 2;
  const float scale = 0.17677669529663689f;
  float4 q4 = ldbf4(Q + (size_t)n * NDIM + col);
  q4.x *= scale; q4.y *= scale; q4.z *= scale; q4.w *= scale;
  int e0 = offs[n], e1 = offs[n + 1];
  float den = 0.f;
  float ax = 0.f, ay = 0.f, az = 0.f, aw = 0.f;
  int e = e0;
  for (; e + 8 <= e1; e += 8) {
    unsigned int kw[8], vw[8];
    #pragma unroll
    for (int j = 0; j < 8; ++j) {
      int s = ssrc[e + j];
      kw[j] = *(const unsigned int*)(K8 + (size_t)s * NDIM + col);
      vw[j] = *(const unsigned int*)(V8 + (size_t)s * NDIM + col);
    }
    float d[8];
    #pragma unroll
    for (int j = 0; j < 8; ++j) {
      f32x2 k01 = e4m3pk<false>(kw[j]);
      f32x2 k23 = e4m3pk<true>(kw[j]);
      d[j] = q4.x * k01[0] + q4.y * k01[1] + q4.z * k23[0] + q4.w * k23[1];
    }
    #pragma unroll
    for (int j = 0; j < 8; ++j) {
      d[j] += __shfl_xor(d[j], 1);
      d[j] += __shfl_xor(d[j], 2);
      d[j] += __shfl_xor(d[j], 4);
    }
    #pragma unroll
    for (int j = 0; j < 8; ++j) {
      float p = __expf(d[j]);
      den += p;
      f32x2 v01 = e4m3pk<false>(vw[j]);
      f32x2 v23 = e4m3pk<true>(vw[j]);
      ax += p * v01[0]; ay += p * v01[1];
      az += p * v23[0]; aw += p * v23[1];
    }
  }
  for (; e + 4 <= e1; e += 4) {
    unsigned int kw[4], vw[4];
    #pragma unroll
    for (int j = 0; j < 4; ++j) {
      int s = ssrc[e + j];
      kw[j] = *(const unsigned int*)(K8 + (size_t)s * NDIM + col);
      vw[j] = *(const unsigned int*)(V8 + (size_t)s * NDIM + col);
    }
    float d[4];
    #pragma unroll
    for (int j = 0; j < 4; ++j) {
      f32x2 k01 = e4m3pk<false>(kw[j]);
      f32x2 k23 = e4m3pk<true>(kw[j]);
      d[j] = q4.x * k01[0] + q4.y * k01[1] + q4.z * k23[0] + q4.w * k23[1];
    }
    #pragma unroll
    for (int j = 0; j < 4; ++j) {
      d[j] += __shfl_xor(d[j], 1);
      d[j] += __shfl_xor(d[j], 2);
      d[j] += __shfl_xor(d[j], 4);
    }
    #pragma unroll
    for (int j = 0; j < 4; ++j) {
      float p = __expf(d[j]);
      den += p;
      f32x2 v01 = e4m3pk<false>(vw[j]);
      f32x2 v23 = e4m3pk<true>(vw[j]);
      ax += p * v01[0]; ay += p * v01[1];
      az += p * v23[0]; aw += p * v23[1];
    }
  }
  for (; e < e1; ++e) {
    int s = ssrc[e];
    unsigned int kw = *(const unsigned int*)(K8 + (size_t)s * NDIM + col);
    unsigned int vw = *(const unsigned int*)(V8 + (size_t)s * NDIM + col);
    f32x2 k01 = e4m3pk<false>(kw);
    f32x2 k23 = e4m3pk<true>(kw);
    float d = q4.x * k01[0] + q4.y * k01[1] + q4.z * k23[0] + q4.w * k23[1];
    d += __shfl_xor(d, 1);
    d += __shfl_xor(d, 2);
    d += __shfl_xor(d, 4);
    float p = __expf(d);
    den += p;
    f32x2 v01 = e4m3pk<false>(vw);
    f32x2 v23 = e4m3pk<true>(vw);
    ax += p * v01[0]; ay += p * v01[1];
    az += p * v23[0]; aw += p * v23[1];
  }
  float inv = (den > 0.f) ? 1.f / den : 0.f;
  stbf4(agg + (size_t)n * NDIM + col, make_float4(ax * inv, ay * inv, az * inv, aw * inv));
}

// ---------- MFMA GEMM: swizzled LDS + XCD swizzle + operand-swapped MFMA for wide stores ----------
// mfma(bf, af): D reg-dim -> output COLS (4 consecutive per lane), lane&15 -> output row.
// EPI: 0 = fp32 float4, 2 = gelu + bf16x4, 3 = qkv split (Q bf16x4, K/V fp8x4), cols pre-permuted
template<int EPI>
__global__ __launch_bounds__(256, 4) void mgemm_k(
    const unsigned short* __restrict__ A1, const unsigned short* __restrict__ A2,
    const unsigned short* __restrict__ Wt, const float* __restrict__ bias,
    float* __restrict__ Cf, unsigned short* __restrict__ Cb,
    unsigned short* __restrict__ Oq, unsigned char* __restrict__ Ok, unsigned char* __restrict__ Ov,
    int M, int K1, int K, int Ncol, int ldb, int nct)
{
  __shared__ unsigned short As[128 * 64];
  __shared__ unsigned short Bs[128 * 64];
  const int tid = threadIdx.x;
  const int lane = tid & 63;
  const int wid = tid >> 6;

  // XCD-aware bijective block swizzle (m204)
  const int nwg = gridDim.x;
  const int q8 = nwg >> 3, r8 = nwg & 7;
  const int xcd = blockIdx.x & 7, idx8 = blockIdx.x >> 3;
  const int swz = (xcd < r8 ? xcd * (q8 + 1) : r8 * (q8 + 1) + (xcd - r8) * q8) + idx8;
  const int bmt = swz / nct;
  const int bnt = swz - bmt * nct;
  const int bm = bmt * 128;
  const int bn = bnt * 128;

  const int wr = (wid >> 1) << 6;
  const int wc = (wid & 1) << 6;
  const int l15 = lane & 15, lhi = lane >> 4;
  const int srow = lane >> 3;
  const int ssl = (((lane & 7) ^ (lane >> 3)) << 3);   // inverse-swizzled slot

  f32x4 acc[4][4];
  #pragma unroll
  for (int i = 0; i < 4; ++i)
    #pragma unroll
    for (int j = 0; j < 4; ++j) acc[i][j] = (f32x4){0.f, 0.f, 0.f, 0.f};

  for (int k0 = 0; k0 < K; k0 += 64) {
    const unsigned short* Ab;
    int ks;
    if (k0 < K1) { Ab = A1; ks = k0; } else { Ab = A2; ks = k0 - K1; }
    #pragma unroll
    for (int t = 0; t < 4; ++t) {
      int qi = wid * 4 + t;
      const unsigned short* ga = Ab + (size_t)(bm + qi * 8 + srow) * 256 + ks + ssl;
      __builtin_amdgcn_global_load_lds(
          (const __attribute__((address_space(1))) void*)ga,
          (__attribute__((address_space(3))) void*)&As[qi * 512], 16, 0, 0);
      const unsigned short* gb = Wt + (size_t)(bn + qi * 8 + srow) * ldb + k0 + ssl;
      __builtin_amdgcn_global_load_lds(
          (const __attribute__((address_space(1))) void*)gb,
          (__attribute__((address_space(3))) void*)&Bs[qi * 512], 16, 0, 0);
    }
    __syncthreads();
    #pragma unroll
    for (int kk = 0; kk < 64; kk += 32) {
      bf16x8 af[4], bfr[4];
      #pragma unroll
      for (int mi = 0; mi < 4; ++mi) {
        int rA = wr + mi * 16 + l15;
        af[mi] = *(const bf16x8*)&As[rA * 64 + ((((kk >> 3) + lhi) ^ (rA & 7)) << 3)];
      }
      #pragma unroll
      for (int ni = 0; ni < 4; ++ni) {
        int rB = wc + ni * 16 + l15;
        bfr[ni] = *(const bf16x8*)&Bs[rB * 64 + ((((kk >> 3) + lhi) ^ (rB & 7)) << 3)];
      }
      #pragma unroll
      for (int mi = 0; mi < 4; ++mi)
        #pragma unroll
        for (int ni = 0; ni < 4; ++ni)
          acc[mi][ni] = __builtin_amdgcn_mfma_f32_16x16x32_bf16(bfr[ni], af[mi], acc[mi][ni], 0, 0, 0);
    }
    __syncthreads();
  }

  // epilogue: lane holds C[bm+wr+mi*16+l15][bn+wc+ni*16+lhi*4 + i] for i=0..3
  #pragma unroll
  for (int ni = 0; ni < 4; ++ni) {
    const int gc0 = bn + wc + ni * 16 + (lhi << 2);
    int seg = 0, jj0 = 0;
    float4 bb;
    if (EPI == 3) {
      seg = gc0 >> 8; jj0 = gc0 & 255;
      int h = jj0 >> 5, t0 = jj0 & 31;
      bb = *(const float4*)&bias[h * 96 + seg * 32 + t0];
    } else {
      bb = *(const float4*)&bias[gc0];
    }
    #pragma unroll
    for (int mi = 0; mi < 4; ++mi) {
      int gr = bm + wr + mi * 16 + l15;
      if (gr >= M) continue;
      float v0 = acc[mi][ni][0] + bb.x;
      float v1 = acc[mi][ni][1] + bb.y;
      float v2 = acc[mi][ni][2] + bb.z;
      float v3 = acc[mi][ni][3] + bb.w;
      if (EPI == 0) {
        *(float4*)&Cf[(size_t)gr * Ncol + gc0] = make_float4(v0, v1, v2, v3);
      } else if (EPI == 2) {
        v0 = 0.5f * v0 * (1.0f + erff(v0 * 0.70710678118654752f));
        v1 = 0.5f * v1 * (1.0f + erff(v1 * 0.70710678118654752f));
        v2 = 0.5f * v2 * (1.0f + erff(v2 * 0.70710678118654752f));
        v3 = 0.5f * v3 * (1.0f + erff(v3 * 0.70710678118654752f));
        *(ull*)&Cb[(size_t)gr * Ncol + gc0] = pk4_bf16(v0, v1, v2, v3);
      } else {
        if (seg == 0) {
          *(ull*)&Oq[(size_t)gr * NDIM + jj0] = pk4_bf16(v0, v1, v2, v3);
        } else {
          unsigned int w = pk4_e4m3(v0, v1, v2, v3);
          unsigned char* dstp = (seg == 1) ? Ok : Ov;
          *(unsigned int*)&dstp[(size_t)gr * NDIM + jj0] = w;
        }
      }
    }
  }
}

extern "C" void kernel_launch(void* const* d_in, const int* in_sizes, int n_in,
                              void* d_out, int out_size, void* d_ws, size_t ws_size,
                              hipStream_t stream) {
  (void)n_in; (void)out_size; (void)ws_size;
  const float* x    = (const float*)d_in[0];
  const int*   src  = (const int*)d_in[1];
  const int*   dst  = (const int*)d_in[2];
  const float* Wqkv = (const float*)d_in[3];
  const float* bqkv = (const float*)d_in[4];
  const float* Wout = (const float*)d_in[5];
  const float* bout = (const float*)d_in[6];
  const float* W1   = (const float*)d_in[7];
  const float* b1   = (const float*)d_in[8];
  const float* W2   = (const float*)d_in[9];
  const float* b2   = (const float*)d_in[10];
  float* out = (float*)d_out;

  const int N = in_sizes[0] / NDIM;   // 50000
  const int E = in_sizes[1];          // 800000
  const int Mp = (N + 127) & ~127;    // 50048
  const int nb = (N + SCB - 1) / SCB;

  char* ws = (char*)d_ws;
  size_t off = 0;
  auto alloc = [&](size_t bytes) -> char* {
    char* p = ws + off;
    off += (bytes + 255) & ~(size_t)255;
    return p;
  };
  unsigned short* xb   = (unsigned short*)alloc((size_t)Mp * NDIM * 2);
  unsigned short* Q    = (unsigned short*)alloc((size_t)Mp * NDIM * 2);
  unsigned short* Kb   = (unsigned short*)alloc((size_t)Mp * NDIM * 2);
  unsigned short* Vb   = (unsigned short*)alloc((size_t)Mp * NDIM * 2);
  unsigned short* wqkvt = (unsigned short*)alloc((size_t)768 * 256 * 2);
  unsigned short* wft   = (unsigned short*)alloc((size_t)256 * 512 * 2);
  unsigned short* w2t   = (unsigned short*)alloc((size_t)256 * 256 * 2);
  float*          bc    = (float*)alloc(256 * 4);
  int* deg    = (int*)alloc((size_t)N * 4);
  int* offs   = (int*)alloc((size_t)(N + 1) * 4);
  int* cursor = (int*)alloc((size_t)N * 4);
  int* ssrc   = (int*)alloc((size_t)E * 4);
  int* bsum   = (int*)alloc((size_t)nb * 4);

  unsigned char* K8 = (unsigned char*)Kb;
  unsigned char* V8 = (unsigned char*)Vb;
  unsigned short* agg = Q;    // attn writes in place over Q
  unsigned short* h1  = Kb;   // Kb dead after attn

  // input/weight prep
  xconv_k<<<(N * NDIM / 8 + 255) / 256, 256, 0, stream>>>(x, xb, N * NDIM / 8);
  wconvqkv_k<<<(768 * 256 + 255) / 256, 256, 0, stream>>>(Wqkv, wqkvt);
  wf1_k<<<256, 256, 0, stream>>>(W1, wft);
  wfc_k<<<256, 256, 0, stream>>>(Wout, W1, wft);
  bfc_k<<<1, 256, 0, stream>>>(bout, b1, W1, bc);
  wconv_k<<<(256 * 256 + 255) / 256, 256, 0, stream>>>(W2, w2t, 256, 256);

  // CSR build
  hipMemsetAsync(deg, 0, (size_t)N * 4, stream);
  hist_k<<<(E + 255) / 256, 256, 0, stream>>>(dst, deg, E);
  bsum_k<<<nb, SCB, 0, stream>>>(deg, bsum, N);
  bscan_k<<<1, 128, 0, stream>>>(bsum, nb);
  offs_k<<<nb, SCB, 0, stream>>>(deg, bsum, offs, N);
  hipMemcpyAsync(cursor, offs, (size_t)N * 4, hipMemcpyDeviceToDevice, stream);
  scatter_k<<<(E + 255) / 256, 256, 0, stream>>>(src, dst, cursor, ssrc, E);

  const int mt = Mp / 128;   // 391

  // QKV projection -> Q (bf16), K8/V8 (fp8); wqkvt column-permuted
  mgemm_k<3><<<mt * 6, 256, 0, stream>>>(
      xb, nullptr, wqkvt, bqkv, nullptr, nullptr, Q, K8, V8, N, 256, 256, 768, 256, 6);

  // edge-softmax aggregation (agg == Q in place)
  attn_k<<<(N + 3) / 4, 256, 0, stream>>>(Q, K8, V8, offs, ssrc, agg, N);

  // FUSED FFN-in: gelu(x@W1a + agg@(Wout@W1b) + bc) -> h1 (bf16)   [Wout GEMM eliminated]
  mgemm_k<2><<<mt * 2, 256, 0, stream>>>(
      xb, agg, wft, bc, nullptr, h1, nullptr, nullptr, nullptr, N, 256, 512, 256, 512, 2);

  // h1 @ W2 + b2 -> out (fp32)
  mgemm_k<0><<<mt * 2, 256, 0, stream>>>(
      h1, nullptr, w2t, b2, out, nullptr, nullptr, nullptr, nullptr, N, 256, 256, 256, 256, 2);
}